// Round 5
// baseline (493.677 us; speedup 1.0000x reference)
//
#include <hip/hip_runtime.h>
#include <hip/hip_bf16.h>
#include <stdint.h>

// Problem constants (fixed by setup_inputs)
#define B_SZ  8
#define N_Q   8192
#define M_PT  2048
#define C1    128
#define C2    256
#define CIN   384      // C1 + C2
#define H_OUT 256
#define R_TOT 65536    // B_SZ * N_Q

typedef __bf16 bf16x8 __attribute__((ext_vector_type(8)));
typedef __bf16 bf16x4 __attribute__((ext_vector_type(4)));
typedef float  f32x4  __attribute__((ext_vector_type(4)));

// Async global->LDS, 16B per lane. LDS dest is wave-uniform base + lane*16.
__device__ __forceinline__ void async_copy16(const void* g, void* l) {
    __builtin_amdgcn_global_load_lds(
        (const __attribute__((address_space(1))) unsigned int*)g,
        (__attribute__((address_space(3))) unsigned int*)l,
        16, 0, 0);
}

// ---------------------------------------------------------------------------
// K1: convert folds (p1/p2 -> bf16, W1 split, W2) + per-batch x-sort of xyz2
// (rank-by-count O(M^2)) + per-batch 256-bin x-CDF of the sorted points
// (pcdf[b][k] = #points with bin(x) < k = first sorted rank in bin k).
// Sort/CDF blocks FIRST (blockIdx 0..71) so they overlap the converts.
// spts[b][rank] = (-2x, -2y, -2z, |p|^2)   (d' operands, bitwise-identical
//                                           to the round-2/3/4 passing kernels)
// sidx[b][rank] = original point index
// ---------------------------------------------------------------------------
__global__ __launch_bounds__(256) void convert_sort(
    const float* __restrict__ xyz2, const float* __restrict__ p1,
    const float* __restrict__ p2,   const float* __restrict__ W1,
    const float* __restrict__ W2,
    __bf16* __restrict__ p1b,  __bf16* __restrict__ p2b,
    __bf16* __restrict__ wb1a, __bf16* __restrict__ wb1b,
    __bf16* __restrict__ wb2,  float4* __restrict__ spts,
    int* __restrict__ sidx,    int* __restrict__ pcdf) {
    const int tid = threadIdx.x;

    if (blockIdx.x < 64) {   // ---- point-sort blocks: (b, chunk-of-256)
        __shared__ __attribute__((aligned(16))) float xs[M_PT];
        const int b  = blockIdx.x >> 3;
        const int ch = blockIdx.x & 7;
        const float* x2 = xyz2 + (size_t)b * M_PT * 3;
#pragma unroll
        for (int j = tid; j < M_PT; j += 256) xs[j] = x2[j * 3];
        __syncthreads();
        const int   i  = ch * 256 + tid;
        const float xi = xs[i];
        const float yi = x2[i * 3 + 1], zi = x2[i * 3 + 2];
        int rank = 0;
#pragma unroll 4
        for (int j = 0; j < M_PT; j += 4) {
            const float4 xv = *(const float4*)&xs[j];
            rank += (xv.x < xi || (xv.x == xi && (j + 0) < i)) ? 1 : 0;
            rank += (xv.y < xi || (xv.y == xi && (j + 1) < i)) ? 1 : 0;
            rank += (xv.z < xi || (xv.z == xi && (j + 2) < i)) ? 1 : 0;
            rank += (xv.w < xi || (xv.w == xi && (j + 3) < i)) ? 1 : 0;
        }
        const float pw = fmaf(xi, xi, fmaf(yi, yi, zi * zi));
        spts[(size_t)b * M_PT + rank] =
            make_float4(-2.f * xi, -2.f * yi, -2.f * zi, pw);
        sidx[(size_t)b * M_PT + rank] = i;
        return;
    }

    if (blockIdx.x < 72) {   // ---- point-CDF blocks: one per batch
        __shared__ int hist[256], offs[256];
        const int b = blockIdx.x - 64;
        const float* x2 = xyz2 + (size_t)b * M_PT * 3;
        hist[tid] = 0;
        __syncthreads();
#pragma unroll
        for (int j = tid; j < M_PT; j += 256) {
            const float x = x2[j * 3];
            int bin = (int)((x + 4.0f) * 32.0f);
            bin = min(max(bin, 0), 255);
            atomicAdd(&hist[bin], 1);
        }
        __syncthreads();
        offs[tid] = hist[tid];
        __syncthreads();
        for (int s = 1; s < 256; s <<= 1) {     // inclusive Hillis-Steele
            const int v = (tid >= s) ? offs[tid - s] : 0;
            __syncthreads();
            offs[tid] += v;
            __syncthreads();
        }
        pcdf[b * 256 + tid] = offs[tid] - hist[tid];   // exclusive scan
        return;
    }

    // ---- convert blocks: cb in [0, 2048)
    const int cb  = blockIdx.x - 72;
    const int gid = cb * 256 + tid;           // 0..524287

    // p2 -> bf16 (4,194,304 elems = 524288 threads x 8)
    {
        const float4* src = (const float4*)p2 + (size_t)gid * 2;
        float4 a = src[0], bb = src[1];
        bf16x8 o;
        o[0]=(__bf16)a.x; o[1]=(__bf16)a.y; o[2]=(__bf16)a.z; o[3]=(__bf16)a.w;
        o[4]=(__bf16)bb.x; o[5]=(__bf16)bb.y; o[6]=(__bf16)bb.z; o[7]=(__bf16)bb.w;
        *(bf16x8*)(p2b + (size_t)gid * 8) = o;
    }
    // W1 split-convert (98304 elems) / W2 convert (65536 elems)
    if (cb < 384) {
        const int e = gid;                       // 0..98303
        const int o = e / 384, k = e - o * 384;
        __bf16 v = (__bf16)W1[e];
        if (k < C1) wb1a[o * C1 + k] = v;
        else        wb1b[o * C2 + (k - C1)] = v;
    } else if (cb < 640) {
        const int e = gid - 98304;               // 0..65535
        wb2[e] = (__bf16)W2[e];
    }
    // p1 -> bf16 (8,388,608 elems = 524288 threads x 16)
    {
        const float4* src = (const float4*)p1 + (size_t)gid * 4;
        float4 a = src[0], bb = src[1], cc = src[2], dd = src[3];
        bf16x8 o0, o1;
        o0[0]=(__bf16)a.x; o0[1]=(__bf16)a.y; o0[2]=(__bf16)a.z; o0[3]=(__bf16)a.w;
        o0[4]=(__bf16)bb.x; o0[5]=(__bf16)bb.y; o0[6]=(__bf16)bb.z; o0[7]=(__bf16)bb.w;
        o1[0]=(__bf16)cc.x; o1[1]=(__bf16)cc.y; o1[2]=(__bf16)cc.z; o1[3]=(__bf16)cc.w;
        o1[4]=(__bf16)dd.x; o1[5]=(__bf16)dd.y; o1[6]=(__bf16)dd.z; o1[7]=(__bf16)dd.w;
        *(bf16x8*)(p1b + (size_t)gid * 16)     = o0;
        *(bf16x8*)(p1b + (size_t)gid * 16 + 8) = o1;
    }
}

// ---------------------------------------------------------------------------
// K2: wave-cooperative sweep KNN — ONE QUERY PER WAVE, 64 lanes scan
// cooperatively (lanes 0..31 sweep left, 32..63 sweep right; 32 consecutive
// ranks per side per iteration => conflict-free consecutive ds_read_b128).
// Each lane keeps a LOCAL top-3 (value+rank) of the points it visited; the
// global top-3 is a subset of the union of lane-local top-3s (any point
// beating a lane's 3rd would itself be globally smaller).  Termination per
// side: all unscanned ranks on a side have true-dist >= (frontier dx)^2
// (x-sorted), so stop when that >= wave-min(lane v2) + |q|^2 + 1e-3 guard
// (wave-min lane-v2 >= global v2 => conservative => sound).  Window start
// comes from the 256-bin x-CDF (no binary search); an off-by-<=bin start
// only adds a few scanned points, bounds stay exact.
// Skew is absorbed at query granularity: a 1500-point straggler query is 24
// iterations of a fully-busy wave, not 190 iterations of one lane.
// d' operands from spts => selection bitwise-identical to passing rounds.
// Block = 4 waves; each wave processes 32 queries; grid = 512.
// ---------------------------------------------------------------------------
__global__ __launch_bounds__(256) void knn_sweep(
    const float* __restrict__ xyz1, const float4* __restrict__ spts,
    const int* __restrict__ sidx,   const int* __restrict__ pcdf,
    float4* __restrict__ w4, int4* __restrict__ gidx4) {
    __shared__ __attribute__((aligned(16))) float4 pts[M_PT];   // 32 KB
    __shared__ int pc[256];
    const int tid  = threadIdx.x;
    const int b    = blockIdx.x >> 6;        // 64 blocks per batch
    const int qc   = blockIdx.x & 63;        // 128 queries per block
    const int wave = tid >> 6, lane = tid & 63;

    {   // stage spts[b] (2048 float4) into LDS, async 16B per lane
        const float4* src = spts + (size_t)b * M_PT;
#pragma unroll
        for (int j = 0; j < 8; ++j)
            async_copy16(src + j * 256 + wave * 64 + lane,
                         (char*)pts + ((j * 256 + wave * 64) << 4));
    }
    pc[tid] = pcdf[b * 256 + tid];
    __syncthreads();

    // preload this wave's 32 queries into lanes 0..31
    float xq = 0.f, yq = 0.f, zq = 0.f;
    const int q0 = qc * 128 + wave * 32;
    if (lane < 32) {
        const float* qp = xyz1 + (size_t)(b * N_Q + q0 + lane) * 3;
        xq = qp[0]; yq = qp[1]; zq = qp[2];
    }
    const int side = lane >> 5, o = lane & 31;

    for (int qi = 0; qi < 32; ++qi) {
        const float qx = __shfl(xq, qi), qy = __shfl(yq, qi),
                    qz = __shfl(zq, qi);
        const float n1q = fmaf(qx, qx, fmaf(qy, qy, qz * qz));
        int kq = (int)((qx + 4.0f) * 32.0f);
        kq = min(max(kq, 0), 255);
        const int lo = pc[kq];

        float v0 = 3.4e38f, v1 = 3.4e38f, v2 = 3.4e38f;
        int   r0 = 0, r1 = 0, r2 = 0;
        int offL = 0, offR = 0;
        bool dl = false, dr = false;

        // cap 68: 68*32 > 2048 per side => every in-range point visited
        // even if the bound never fires (then the result is exact anyway).
#pragma unroll 1
        for (int it = 0; it < 68 && !(dl && dr); ++it) {
            const int  myr = side ? (lo + offR + o) : (lo - 1 - offL - o);
            const bool act = side ? (!dr && myr < M_PT) : (!dl && myr >= 0);
            const int  rk  = myr & (M_PT - 1);
            const float4 p = pts[rk];
            float d = fmaf(p.x, qx, fmaf(p.y, qy, fmaf(p.z, qz, p.w)));
            d = act ? d : 3.4e38f;
            const bool c0 = d < v0, c1 = d < v1, c2 = d < v2;
            const float n1v = __builtin_amdgcn_fmed3f(d, v0, v1);
            const float n2v = __builtin_amdgcn_fmed3f(d, v1, v2);
            r2 = c1 ? r1 : (c2 ? rk : r2);
            r1 = c0 ? r0 : (c1 ? rk : r1);
            r0 = c0 ? rk : r0;
            v0 = fminf(d, v0); v1 = n1v; v2 = n2v;
            if (!dl) offL += 32;
            if (!dr) offR += 32;
            // conservative global v2: wave-min of lane-local v2
            float vv = v2;
#pragma unroll
            for (int s = 1; s < 64; s <<= 1)
                vv = fminf(vv, __shfl_xor(vv, s));
            const float thr = fminf(vv + n1q + 1e-3f, 3.0e38f);
            // frontier bounds (wave-uniform broadcast reads)
            const int fL = lo - 1 - offL, fR = lo + offR;
            const float xl = pts[max(fL, 0)].x;
            const float xr = pts[min(fR, M_PT - 1)].x;
            const float tl = fmaxf(fmaf(0.5f, xl, qx), 0.f);   // qx - x[fL]
            const float tr = fmaxf(-fmaf(0.5f, xr, qx), 0.f);  // x[fR] - qx
            const float bl = (fL >= 0)   ? tl * tl : 3.4e38f;
            const float br = (fR < M_PT) ? tr * tr : 3.4e38f;
            dl = dl || (bl >= thr);
            dr = dr || (br >= thr);
        }

        // extract global top-3: 3x (wave-min + ballot-argmin + evict)
        float gv0, gv1, gv2; int gr0, gr1, gr2;
#pragma unroll
        for (int k = 0; k < 3; ++k) {
            float vv = v0;
#pragma unroll
            for (int s = 1; s < 64; s <<= 1)
                vv = fminf(vv, __shfl_xor(vv, s));
            const unsigned long long mm = __ballot(v0 == vv);
            const int ln = (int)__ffsll((unsigned long long)mm) - 1;
            const int rr = __shfl(r0, ln);
            if (k == 0) { gv0 = vv; gr0 = rr; }
            else if (k == 1) { gv1 = vv; gr1 = rr; }
            else { gv2 = vv; gr2 = rr; }
            if (lane == ln) { v0 = v1; v1 = v2; v2 = 3.4e38f; r0 = r1; r1 = r2; }
        }

        if (lane == 0) {   // weights: identical formula to passing rounds
            const int qid = b * N_Q + q0 + qi;
            const int i0 = sidx[b * M_PT + gr0];
            const int i1 = sidx[b * M_PT + gr1];
            const int i2 = sidx[b * M_PT + gr2];
            const float rr0 = 1.f / ((gv0 + n1q) + 1e-8f);
            const float rr1 = 1.f / ((gv1 + n1q) + 1e-8f);
            const float rr2 = 1.f / ((gv2 + n1q) + 1e-8f);
            const float rs  = 1.f / (rr0 + rr1 + rr2);
            w4[qid]    = make_float4(rr0 * rs, rr1 * rs, rr2 * rs, 0.f);
            gidx4[qid] = make_int4(i0, i1, i2, 0);
        }
    }
}

// ---------------------------------------------------------------------------
// bf16 MFMA GEMM (m97 structure), optional fused BN-stats partials.
// C stride is H_OUT=256 for all uses (Z, y2).  grid = (rows/128)*2.
// ---------------------------------------------------------------------------
template <int K, bool STATS>
__global__ __launch_bounds__(256, 2) void gemm_bt(const __bf16* __restrict__ A,
                                                  const __bf16* __restrict__ Bw,
                                                  __bf16* __restrict__ Cout,
                                                  float* __restrict__ partS,
                                                  float* __restrict__ partQ) {
    __shared__ __attribute__((aligned(16))) __bf16 As[128 * 32];
    __shared__ __attribute__((aligned(16))) __bf16 Bs[128 * 32];
    const int tid  = threadIdx.x;
    const int wave = tid >> 6, lane = tid & 63;
    const int wm = wave >> 1, wn = wave & 1;
    const int quad = lane >> 4, r16 = lane & 15;
    const int bx = blockIdx.x & 1, by = blockIdx.x >> 1;
    const int l4 = lane >> 2, lk = (lane & 3) * 8;

    f32x4 acc[4][4] = {};

    const __bf16* gA = A  + (size_t)(by * 128 + wave * 32 + l4) * K + lk;
    const __bf16* gB = Bw + (size_t)(bx * 128 + wave * 32 + l4) * K + lk;
    char* lA = (char*)As + wave * 2048;
    char* lB = (char*)Bs + wave * 2048;

    for (int k0 = 0; k0 < K; k0 += 32) {
        async_copy16(gA + k0,                  lA);
        async_copy16(gA + k0 + (size_t)16 * K, lA + 1024);
        async_copy16(gB + k0,                  lB);
        async_copy16(gB + k0 + (size_t)16 * K, lB + 1024);
        __syncthreads();

        bf16x8 af[4], bf[4];
#pragma unroll
        for (int t = 0; t < 4; ++t)
            af[t] = *(const bf16x8*)(As + (wm * 64 + t * 16 + r16) * 32 + quad * 8);
#pragma unroll
        for (int u = 0; u < 4; ++u)
            bf[u] = *(const bf16x8*)(Bs + (wn * 64 + u * 16 + r16) * 32 + quad * 8);
#pragma unroll
        for (int t = 0; t < 4; ++t)
#pragma unroll
            for (int u = 0; u < 4; ++u)
                acc[t][u] = __builtin_amdgcn_mfma_f32_16x16x32_bf16(af[t], bf[u], acc[t][u], 0, 0, 0);
        __syncthreads();
    }

    // C/D layout col=lane&15, row=(lane>>4)*4+reg [m89-verified]
#pragma unroll
    for (int t = 0; t < 4; ++t) {
#pragma unroll
        for (int u = 0; u < 4; ++u) {
            const int col = bx * 128 + wn * 64 + u * 16 + r16;
#pragma unroll
            for (int r = 0; r < 4; ++r) {
                const int row = by * 128 + wm * 64 + t * 16 + quad * 4 + r;
                Cout[(size_t)row * H_OUT + col] = (__bf16)acc[t][u][r];
            }
        }
    }

    if constexpr (STATS) {
        float* redS = (float*)As;          // [col(128)][slot(8)]
        float* redQ = ((float*)As) + 1024;
        const int slot = wm * 4 + quad;
#pragma unroll
        for (int u = 0; u < 4; ++u) {
            float s = 0.f, qq = 0.f;
#pragma unroll
            for (int t = 0; t < 4; ++t)
#pragma unroll
                for (int r = 0; r < 4; ++r) { float v = acc[t][u][r]; s += v; qq = fmaf(v, v, qq); }
            const int col = wn * 64 + u * 16 + r16;
            redS[col * 8 + slot] = s;
            redQ[col * 8 + slot] = qq;
        }
        __syncthreads();
        if (tid < 128) {
            float s = 0.f, qq = 0.f;
#pragma unroll
            for (int k = 0; k < 8; ++k) { s += redS[tid * 8 + k]; qq += redQ[tid * 8 + k]; }
            partS[(size_t)blockIdx.x * 128 + tid] = s;
            partQ[(size_t)blockIdx.x * 128 + tid] = qq;
        }
    }
}

// ---------------------------------------------------------------------------
// GEMM-A (K=128) + fused interpolation epilogue + BN-stats:
//   y1 = p1b @ wb1a^T + sum_k w_k * Z[idx_k]      (linearity of interp)
// Z rows are L2-resident (8.4 MB); gathers are 16-lane-contiguous 2B loads.
// grid = 512*2 = 1024 blocks of 256.  (idx/w come directly from knn_sweep.)
// ---------------------------------------------------------------------------
__global__ __launch_bounds__(256, 2) void gemm_a_int(
    const __bf16* __restrict__ A,  const __bf16* __restrict__ Bw,
    const __bf16* __restrict__ zb, const int4* __restrict__ gidx4,
    const float4* __restrict__ w4, __bf16* __restrict__ Cout,
    float* __restrict__ partS, float* __restrict__ partQ) {
    constexpr int K = C1;   // 128
    __shared__ __attribute__((aligned(16))) __bf16 As[128 * 32];
    __shared__ __attribute__((aligned(16))) __bf16 Bs[128 * 32];
    const int tid  = threadIdx.x;
    const int wave = tid >> 6, lane = tid & 63;
    const int wm = wave >> 1, wn = wave & 1;
    const int quad = lane >> 4, r16 = lane & 15;
    const int bx = blockIdx.x & 1, by = blockIdx.x >> 1;
    const int l4 = lane >> 2, lk = (lane & 3) * 8;

    f32x4 acc[4][4] = {};

    const __bf16* gA = A  + (size_t)(by * 128 + wave * 32 + l4) * K + lk;
    const __bf16* gB = Bw + (size_t)(bx * 128 + wave * 32 + l4) * K + lk;
    char* lA = (char*)As + wave * 2048;
    char* lB = (char*)Bs + wave * 2048;

    for (int k0 = 0; k0 < K; k0 += 32) {
        async_copy16(gA + k0,                  lA);
        async_copy16(gA + k0 + (size_t)16 * K, lA + 1024);
        async_copy16(gB + k0,                  lB);
        async_copy16(gB + k0 + (size_t)16 * K, lB + 1024);
        __syncthreads();

        bf16x8 af[4], bf[4];
#pragma unroll
        for (int t = 0; t < 4; ++t)
            af[t] = *(const bf16x8*)(As + (wm * 64 + t * 16 + r16) * 32 + quad * 8);
#pragma unroll
        for (int u = 0; u < 4; ++u)
            bf[u] = *(const bf16x8*)(Bs + (wn * 64 + u * 16 + r16) * 32 + quad * 8);
#pragma unroll
        for (int t = 0; t < 4; ++t)
#pragma unroll
            for (int u = 0; u < 4; ++u)
                acc[t][u] = __builtin_amdgcn_mfma_f32_16x16x32_bf16(af[t], bf[u], acc[t][u], 0, 0, 0);
        __syncthreads();
    }

    // stage per-row (idx0..2, w0..2) into As (4 KB of the free 8 KB)
    if (tid < 128) {
        const int q = by * 128 + tid;
        ((int4*)As)[tid * 2]       = gidx4[q];
        ((float4*)As)[tid * 2 + 1] = w4[q];
    }
    __syncthreads();

    // add interpolated Z rows into the accumulators
    const int bbase = (by >> 6) * M_PT;   // 64 row-blocks per batch
#pragma unroll
    for (int t = 0; t < 4; ++t) {
#pragma unroll
        for (int r = 0; r < 4; ++r) {
            const int rl = wm * 64 + t * 16 + quad * 4 + r;   // row-in-block
            const int4   ii = ((const int4*)As)[rl * 2];      // broadcast read
            const float4 ww = ((const float4*)As)[rl * 2 + 1];
            const __bf16* z0 = zb + (size_t)(bbase + ii.x) * H_OUT;
            const __bf16* z1 = zb + (size_t)(bbase + ii.y) * H_OUT;
            const __bf16* z2 = zb + (size_t)(bbase + ii.z) * H_OUT;
#pragma unroll
            for (int u = 0; u < 4; ++u) {
                const int col = bx * 128 + wn * 64 + u * 16 + r16;
                acc[t][u][r] += ww.x * (float)z0[col] + ww.y * (float)z1[col]
                              + ww.z * (float)z2[col];
            }
        }
    }

    // C store (bf16 y1)
#pragma unroll
    for (int t = 0; t < 4; ++t) {
#pragma unroll
        for (int u = 0; u < 4; ++u) {
            const int col = bx * 128 + wn * 64 + u * 16 + r16;
#pragma unroll
            for (int r = 0; r < 4; ++r) {
                const int row = by * 128 + wm * 64 + t * 16 + quad * 4 + r;
                Cout[(size_t)row * H_OUT + col] = (__bf16)acc[t][u][r];
            }
        }
    }

    __syncthreads();   // idx/w reads done before stats overwrite As
    float* redS = (float*)As;
    float* redQ = ((float*)As) + 1024;
    const int slot = wm * 4 + quad;
#pragma unroll
    for (int u = 0; u < 4; ++u) {
        float s = 0.f, qq = 0.f;
#pragma unroll
        for (int t = 0; t < 4; ++t)
#pragma unroll
            for (int r = 0; r < 4; ++r) { float v = acc[t][u][r]; s += v; qq = fmaf(v, v, qq); }
        const int col = wn * 64 + u * 16 + r16;
        redS[col * 8 + slot] = s;
        redQ[col * 8 + slot] = qq;
    }
    __syncthreads();
    if (tid < 128) {
        float s = 0.f, qq = 0.f;
#pragma unroll
        for (int k = 0; k < 8; ++k) { s += redS[tid * 8 + k]; qq += redQ[tid * 8 + k]; }
        partS[(size_t)blockIdx.x * 128 + tid] = s;
        partQ[(size_t)blockIdx.x * 128 + tid] = qq;
    }
}

// ---------------------------------------------------------------------------
// fold per-block partials -> per-channel scale/shift.  One block per channel.
// channel c lives in gemm-blocks bid = p*2 + (c>>7), entry (c&127); p<512.
// ---------------------------------------------------------------------------
__global__ __launch_bounds__(256) void bn_finalize(const float* __restrict__ pS,
                                                   const float* __restrict__ pQ,
                                                   const float* __restrict__ gamma,
                                                   const float* __restrict__ beta,
                                                   float* __restrict__ sc,
                                                   float* __restrict__ sh) {
    __shared__ float rs[256], rq[256];
    const int c = blockIdx.x;
    const int t = threadIdx.x;
    const int half = c >> 7, lo = c & 127;
    const size_t o1 = (size_t)(2 * t + half) * 128 + lo;
    const size_t o2 = (size_t)(2 * (t + 256) + half) * 128 + lo;
    rs[t] = pS[o1] + pS[o2];
    rq[t] = pQ[o1] + pQ[o2];
    __syncthreads();
    for (int k = 128; k > 0; k >>= 1) {
        if (t < k) { rs[t] += rs[t + k]; rq[t] += rq[t + k]; }
        __syncthreads();
    }
    if (t == 0) {
        const float inv = 1.f / (float)R_TOT;
        float mean = rs[0] * inv;
        float var  = rq[0] * inv - mean * mean;
        float a    = gamma[c] * rsqrtf(var + 1e-5f);
        sc[c] = a;
        sh[c] = beta[c] - mean * a;
    }
}

// ---------------------------------------------------------------------------
// apply BN+ReLU in place (bf16, layer-1 intermediate)
// ---------------------------------------------------------------------------
__global__ __launch_bounds__(256) void apply_bf16(__bf16* __restrict__ y,
                                                  const float* __restrict__ sc,
                                                  const float* __restrict__ sh) {
    __shared__ float scs[256], shs[256];
    scs[threadIdx.x] = sc[threadIdx.x];
    shs[threadIdx.x] = sh[threadIdx.x];
    __syncthreads();
    size_t i = ((size_t)blockIdx.x * 256 + threadIdx.x) * 8;
    int c0 = (int)(i & 255);
    bf16x8 v = *(const bf16x8*)(y + i);
#pragma unroll
    for (int e = 0; e < 8; ++e) {
        float f = fmaf((float)v[e], scs[c0 + e], shs[c0 + e]);
        v[e] = (__bf16)fmaxf(f, 0.f);
    }
    *(bf16x8*)(y + i) = v;
}

// ---------------------------------------------------------------------------
// apply BN+ReLU reading bf16 y2, writing fp32 output
// ---------------------------------------------------------------------------
__global__ __launch_bounds__(256) void apply_out(const __bf16* __restrict__ y,
                                                 const float* __restrict__ sc,
                                                 const float* __restrict__ sh,
                                                 float* __restrict__ out) {
    __shared__ float scs[256], shs[256];
    scs[threadIdx.x] = sc[threadIdx.x];
    shs[threadIdx.x] = sh[threadIdx.x];
    __syncthreads();
    size_t i = ((size_t)blockIdx.x * 256 + threadIdx.x) * 8;
    int c0 = (int)(i & 255);
    bf16x8 v = *(const bf16x8*)(y + i);
    f32x4 o0, o1;
#pragma unroll
    for (int e = 0; e < 4; ++e)
        o0[e] = fmaxf(fmaf((float)v[e], scs[c0 + e], shs[c0 + e]), 0.f);
#pragma unroll
    for (int e = 0; e < 4; ++e)
        o1[e] = fmaxf(fmaf((float)v[4 + e], scs[c0 + 4 + e], shs[c0 + 4 + e]), 0.f);
    *(f32x4*)(out + i)     = o0;
    *(f32x4*)(out + i + 4) = o1;
}

// ---------------------------------------------------------------------------
extern "C" void kernel_launch(void* const* d_in, const int* in_sizes, int n_in,
                              void* d_out, int out_size, void* d_ws, size_t ws_size,
                              hipStream_t stream) {
    const float* xyz1 = (const float*)d_in[0];
    const float* xyz2 = (const float*)d_in[1];
    const float* p1   = (const float*)d_in[2];
    const float* p2   = (const float*)d_in[3];
    const float* W1   = (const float*)d_in[4];
    // d_in[5] = b1  (cancels in batch-norm)
    const float* g1   = (const float*)d_in[6];
    const float* be1  = (const float*)d_in[7];
    const float* W2   = (const float*)d_in[8];
    // d_in[9] = b2  (cancels in batch-norm)
    const float* g2   = (const float*)d_in[10];
    const float* be2  = (const float*)d_in[11];
    float* out = (float*)d_out;

    // workspace layout (16B aligned), max ~76.9 MB:
    //   gidx4/spts/sidx/pcdf live in the y2b overlay region (all dead after
    //   gemm_a_int / knn_sweep, before gemm_bt<H_OUT> writes y2b)
    char* ws = (char*)d_ws;
    __bf16* y1b   = (__bf16*)(ws);                     // 33,554,432
    int4*   gidx4 = (int4*)  (ws + 33554432);          //  1,048,576
    float4* spts  = (float4*)(ws + 34603008);          //    262,144
    int*    sidx  = (int*)   (ws + 34865152);          //     65,536
    int*    pcdf  = (int*)   (ws + 34930688);          //      8,192
    __bf16* zb    = (__bf16*)(ws + 41943040);          //  8,388,608
    float4* w4    = (float4*)(ws + 50331648);          //  1,048,576
    __bf16* p2b   = (__bf16*)(ws + 51380224);          //  8,388,608
    __bf16* p1b   = (__bf16*)(ws + 59768832);          // 16,777,216
    __bf16* y2b   = (__bf16*)(ws + 33554432);          // 33,554,432 (overlay)
    __bf16* wb1a  = (__bf16*)(ws + 76546048);          //     65,536
    __bf16* wb1b  = (__bf16*)(ws + 76611584);          //    131,072
    __bf16* wb2   = (__bf16*)(ws + 76742656);          //    131,072
    float*  sc1   = (float*) (ws + 76873728);
    float*  sh1   = sc1 + 256;
    float*  sc2   = sc1 + 512;
    float*  sh2   = sc1 + 768;

    float* partS1 = (float*)d_out;            // d_out dead until apply_out
    float* partQ1 = partS1 + 131072;
    float* partS2 = partS1 + 262144;
    float* partQ2 = partS1 + 393216;

    convert_sort<<<2120, 256, 0, stream>>>(xyz2, p1, p2, W1, W2,
                                           p1b, p2b, wb1a, wb1b, wb2,
                                           spts, sidx, pcdf);
    knn_sweep<<<512, 256, 0, stream>>>(xyz1, spts, sidx, pcdf, w4, gidx4);

    gemm_bt<C2, false><<<256, 256, 0, stream>>>(p2b, wb1b, zb, nullptr, nullptr);
    gemm_a_int<<<1024, 256, 0, stream>>>(p1b, wb1a, zb, gidx4, w4, y1b,
                                         partS1, partQ1);
    bn_finalize<<<256, 256, 0, stream>>>(partS1, partQ1, g1, be1, sc1, sh1);
    apply_bf16<<<8192, 256, 0, stream>>>(y1b, sc1, sh1);

    gemm_bt<H_OUT, true><<<1024, 256, 0, stream>>>(y1b, wb2, y2b, partS2, partQ2);
    bn_finalize<<<256, 256, 0, stream>>>(partS2, partQ2, g2, be2, sc2, sh2);
    apply_out<<<8192, 256, 0, stream>>>(y2b, sc2, sh2, out);
}

// Round 6
// 373.549 us; speedup vs baseline: 1.3216x; 1.3216x over previous
//
#include <hip/hip_runtime.h>
#include <hip/hip_bf16.h>
#include <stdint.h>

// Problem constants (fixed by setup_inputs)
#define B_SZ  8
#define N_Q   8192
#define M_PT  2048
#define C1    128
#define C2    256
#define CIN   384      // C1 + C2
#define H_OUT 256
#define R_TOT 65536    // B_SZ * N_Q

typedef __bf16 bf16x8 __attribute__((ext_vector_type(8)));
typedef __bf16 bf16x4 __attribute__((ext_vector_type(4)));
typedef float  f32x4  __attribute__((ext_vector_type(4)));

// Async global->LDS, 16B per lane. LDS dest is wave-uniform base + lane*16.
__device__ __forceinline__ void async_copy16(const void* g, void* l) {
    __builtin_amdgcn_global_load_lds(
        (const __attribute__((address_space(1))) unsigned int*)g,
        (__attribute__((address_space(3))) unsigned int*)l,
        16, 0, 0);
}

__device__ __forceinline__ unsigned long long shfl_xor64(unsigned long long v,
                                                         int s) {
    const unsigned lo = (unsigned)v, hi = (unsigned)(v >> 32);
    const unsigned ol = __shfl_xor(lo, s), oh = __shfl_xor(hi, s);
    return ((unsigned long long)oh << 32) | ol;
}

// ---------------------------------------------------------------------------
// K1: convert folds (p1/p2 -> bf16, W1 split, W2) + per-batch x-sort of xyz2
// (rank-by-count O(M^2)) + per-batch 256-bin x-CDF of the sorted points
// (pcdf[b][k] = first sorted rank in bin k).  Sort/CDF blocks FIRST
// (blockIdx 0..71) so they overlap the streaming converts.
// spts[b][rank] = (-2x, -2y, -2z, |p|^2)   (d' operands, bitwise-identical
//                                           to the round-2..5 passing kernels)
// sidx[b][rank] = original point index
// ---------------------------------------------------------------------------
__global__ __launch_bounds__(256) void convert_sort(
    const float* __restrict__ xyz2, const float* __restrict__ p1,
    const float* __restrict__ p2,   const float* __restrict__ W1,
    const float* __restrict__ W2,
    __bf16* __restrict__ p1b,  __bf16* __restrict__ p2b,
    __bf16* __restrict__ wb1a, __bf16* __restrict__ wb1b,
    __bf16* __restrict__ wb2,  float4* __restrict__ spts,
    int* __restrict__ sidx,    int* __restrict__ pcdf) {
    const int tid = threadIdx.x;

    if (blockIdx.x < 64) {   // ---- point-sort blocks: (b, chunk-of-256)
        __shared__ __attribute__((aligned(16))) float xs[M_PT];
        const int b  = blockIdx.x >> 3;
        const int ch = blockIdx.x & 7;
        const float* x2 = xyz2 + (size_t)b * M_PT * 3;
#pragma unroll
        for (int j = tid; j < M_PT; j += 256) xs[j] = x2[j * 3];
        __syncthreads();
        const int   i  = ch * 256 + tid;
        const float xi = xs[i];
        const float yi = x2[i * 3 + 1], zi = x2[i * 3 + 2];
        int rank = 0;
#pragma unroll 4
        for (int j = 0; j < M_PT; j += 4) {
            const float4 xv = *(const float4*)&xs[j];
            rank += (xv.x < xi || (xv.x == xi && (j + 0) < i)) ? 1 : 0;
            rank += (xv.y < xi || (xv.y == xi && (j + 1) < i)) ? 1 : 0;
            rank += (xv.z < xi || (xv.z == xi && (j + 2) < i)) ? 1 : 0;
            rank += (xv.w < xi || (xv.w == xi && (j + 3) < i)) ? 1 : 0;
        }
        const float pw = fmaf(xi, xi, fmaf(yi, yi, zi * zi));
        spts[(size_t)b * M_PT + rank] =
            make_float4(-2.f * xi, -2.f * yi, -2.f * zi, pw);
        sidx[(size_t)b * M_PT + rank] = i;
        return;
    }

    if (blockIdx.x < 72) {   // ---- point-CDF blocks: one per batch
        __shared__ int hist[256], offs[256];
        const int b = blockIdx.x - 64;
        const float* x2 = xyz2 + (size_t)b * M_PT * 3;
        hist[tid] = 0;
        __syncthreads();
#pragma unroll
        for (int j = tid; j < M_PT; j += 256) {
            const float x = x2[j * 3];
            int bin = (int)((x + 4.0f) * 32.0f);
            bin = min(max(bin, 0), 255);
            atomicAdd(&hist[bin], 1);
        }
        __syncthreads();
        offs[tid] = hist[tid];
        __syncthreads();
        for (int s = 1; s < 256; s <<= 1) {     // inclusive Hillis-Steele
            const int v = (tid >= s) ? offs[tid - s] : 0;
            __syncthreads();
            offs[tid] += v;
            __syncthreads();
        }
        pcdf[b * 256 + tid] = offs[tid] - hist[tid];   // exclusive scan
        return;
    }

    // ---- convert blocks: cb in [0, 2048)
    const int cb  = blockIdx.x - 72;
    const int gid = cb * 256 + tid;           // 0..524287

    // p2 -> bf16 (4,194,304 elems = 524288 threads x 8)
    {
        const float4* src = (const float4*)p2 + (size_t)gid * 2;
        float4 a = src[0], bb = src[1];
        bf16x8 o;
        o[0]=(__bf16)a.x; o[1]=(__bf16)a.y; o[2]=(__bf16)a.z; o[3]=(__bf16)a.w;
        o[4]=(__bf16)bb.x; o[5]=(__bf16)bb.y; o[6]=(__bf16)bb.z; o[7]=(__bf16)bb.w;
        *(bf16x8*)(p2b + (size_t)gid * 8) = o;
    }
    // W1 split-convert (98304 elems) / W2 convert (65536 elems)
    if (cb < 384) {
        const int e = gid;                       // 0..98303
        const int o = e / 384, k = e - o * 384;
        __bf16 v = (__bf16)W1[e];
        if (k < C1) wb1a[o * C1 + k] = v;
        else        wb1b[o * C2 + (k - C1)] = v;
    } else if (cb < 640) {
        const int e = gid - 98304;               // 0..65535
        wb2[e] = (__bf16)W2[e];
    }
    // p1 -> bf16 (8,388,608 elems = 524288 threads x 16)
    {
        const float4* src = (const float4*)p1 + (size_t)gid * 4;
        float4 a = src[0], bb = src[1], cc = src[2], dd = src[3];
        bf16x8 o0, o1;
        o0[0]=(__bf16)a.x; o0[1]=(__bf16)a.y; o0[2]=(__bf16)a.z; o0[3]=(__bf16)a.w;
        o0[4]=(__bf16)bb.x; o0[5]=(__bf16)bb.y; o0[6]=(__bf16)bb.z; o0[7]=(__bf16)bb.w;
        o1[0]=(__bf16)cc.x; o1[1]=(__bf16)cc.y; o1[2]=(__bf16)cc.z; o1[3]=(__bf16)cc.w;
        o1[4]=(__bf16)dd.x; o1[5]=(__bf16)dd.y; o1[6]=(__bf16)dd.z; o1[7]=(__bf16)dd.w;
        *(bf16x8*)(p1b + (size_t)gid * 16)     = o0;
        *(bf16x8*)(p1b + (size_t)gid * 16 + 8) = o1;
    }
}

// ---------------------------------------------------------------------------
// K2: wave-cooperative sweep KNN, v2.  One query per wave at a time (8 per
// wave serially); lanes 0..31 sweep left, 32..63 right, 32 consecutive ranks
// per side per iteration (conflict-free).  Lane keeps a LOCAL top-3
// (value+rank); global top-3 c= union of lane-local top-3s.
// CHANGES vs round-5 (which was latency-bound at 18K cy/query):
//  * termination: bl >= min_lanes(v2)+c  <=>  __any(bl >= v2_lane + c)
//    (exact: the argmin lane is the witness; +c monotone in fp) -- one
//    v_cmp+SALU instead of a 6-deep shfl_xor chain per iteration.
//  * extraction: pack (monotone-mapped fp32, rank) in u64; 3x (6-step u64
//    min-reduce + owner-evict by equality; rank uniqueness => unique owner).
//    No ballots/readlanes.  Tie choice differs from round-5 only on exact
//    fp ties (equal value => equal weight => output unchanged).
//  * occupancy: grid 2048 (32 q/block) -> 4 blocks/CU resident (33KB LDS),
//    4 waves/SIMD of latency hiding (was 2).
//  * per-lane point prefetch: next float4 issued right after advance.
// Block = 4 waves; each wave serves 8 queries; grid = 2048.
// ---------------------------------------------------------------------------
__global__ __launch_bounds__(256) void knn_sweep(
    const float* __restrict__ xyz1, const float4* __restrict__ spts,
    const int* __restrict__ sidx,   const int* __restrict__ pcdf,
    float4* __restrict__ w4, int4* __restrict__ gidx4) {
    __shared__ __attribute__((aligned(16))) float4 pts[M_PT];   // 32 KB
    __shared__ int pc[256];
    const int tid  = threadIdx.x;
    const int b    = blockIdx.x >> 8;        // 256 blocks per batch
    const int qc   = blockIdx.x & 255;       // 32 queries per block
    const int wave = tid >> 6, lane = tid & 63;

    {   // stage spts[b] (2048 float4) into LDS, async 16B per lane
        const float4* src = spts + (size_t)b * M_PT;
#pragma unroll
        for (int j = 0; j < 8; ++j)
            async_copy16(src + j * 256 + wave * 64 + lane,
                         (char*)pts + ((j * 256 + wave * 64) << 4));
    }
    pc[tid] = pcdf[b * 256 + tid];
    __syncthreads();

    // preload this wave's 8 queries into lanes 0..7
    float xq = 0.f, yq = 0.f, zq = 0.f;
    const int q0 = qc * 32 + wave * 8;
    if (lane < 8) {
        const float* qp = xyz1 + (size_t)(b * N_Q + q0 + lane) * 3;
        xq = qp[0]; yq = qp[1]; zq = qp[2];
    }
    const int side = lane >> 5, o = lane & 31;

#pragma unroll 1
    for (int qi = 0; qi < 8; ++qi) {
        const float qx = __shfl(xq, qi), qy = __shfl(yq, qi),
                    qz = __shfl(zq, qi);
        const float n1q = fmaf(qx, qx, fmaf(qy, qy, qz * qz));
        int kq = (int)((qx + 4.0f) * 32.0f);
        kq = min(max(kq, 0), 255);
        const int lo = pc[kq];

        float v0 = 3.4e38f, v1 = 3.4e38f, v2 = 3.4e38f;
        int   r0 = 0, r1 = 0, r2 = 0;
        int offL = 0, offR = 0;
        bool dl = false, dr = false;
        int myr = side ? (lo + o) : (lo - 1 - o);
        float4 pcur = pts[myr & (M_PT - 1)];

        // cap 68: 68*32 > 2048 per side => full coverage even w/o early-out
#pragma unroll 1
        for (int it = 0; it < 68 && !(dl && dr); ++it) {
            const bool act = side ? (!dr && myr < M_PT) : (!dl && myr >= 0);
            const int  rk  = myr & (M_PT - 1);
            float d = fmaf(pcur.x, qx,
                      fmaf(pcur.y, qy, fmaf(pcur.z, qz, pcur.w)));
            d = act ? d : 3.4e38f;
            const bool c0 = d < v0, c1 = d < v1, c2 = d < v2;
            const float n1v = __builtin_amdgcn_fmed3f(d, v0, v1);
            const float n2v = __builtin_amdgcn_fmed3f(d, v1, v2);
            r2 = c1 ? r1 : (c2 ? rk : r2);
            r1 = c0 ? r0 : (c1 ? rk : r1);
            r0 = c0 ? rk : r0;
            v0 = fminf(d, v0); v1 = n1v; v2 = n2v;
            // advance (dl/dr wave-uniform) + prefetch next point
            offL += dl ? 0 : 32;
            offR += dr ? 0 : 32;
            myr  = side ? (lo + offR + o) : (lo - 1 - offL - o);
            pcur = pts[myr & (M_PT - 1)];
            // frontier bounds (wave-uniform broadcast reads)
            const int fL = lo - 1 - offL, fR = lo + offR;
            const float xl = pts[max(fL, 0)].x;
            const float xr = pts[min(fR, M_PT - 1)].x;
            const float tl = fmaxf(fmaf(0.5f, xl, qx), 0.f);   // qx - x[fL]
            const float tr = fmaxf(-fmaf(0.5f, xr, qx), 0.f);  // x[fR] - qx
            const float bl = (fL >= 0)   ? tl * tl : 3.4e38f;
            const float br = (fR < M_PT) ? tr * tr : 3.4e38f;
            // stop when bound >= min_lane(v2) + n1q + guard  (exact via any)
            dl = dl || (__any(bl >= v2 + n1q + 1e-3f) != 0);
            dr = dr || (__any(br >= v2 + n1q + 1e-3f) != 0);
        }

        // ---- extraction: pack (mono(v), rank) u64; 3x min-reduce + evict
        unsigned u0 = __float_as_uint(v0), u1 = __float_as_uint(v1),
                 u2 = __float_as_uint(v2);
        u0 ^= ((unsigned)((int)u0 >> 31)) | 0x80000000u;
        u1 ^= ((unsigned)((int)u1 >> 31)) | 0x80000000u;
        u2 ^= ((unsigned)((int)u2 >> 31)) | 0x80000000u;
        unsigned long long p0 = ((unsigned long long)u0 << 32) | (unsigned)r0;
        unsigned long long p1 = ((unsigned long long)u1 << 32) | (unsigned)r1;
        unsigned long long p2 = ((unsigned long long)u2 << 32) | (unsigned)r2;

        float gv0, gv1, gv2; int gr0, gr1, gr2;
#pragma unroll
        for (int k = 0; k < 3; ++k) {
            unsigned long long m = p0;
#pragma unroll
            for (int s = 1; s < 64; s <<= 1) {
                const unsigned long long t = shfl_xor64(m, s);
                m = (t < m) ? t : m;
            }
            const int      rr = (int)(m & 0xFFFFFFFFu);
            unsigned       hb = (unsigned)(m >> 32);
            hb = (hb & 0x80000000u) ? (hb ^ 0x80000000u) : ~hb;   // un-mono
            const float vv = __uint_as_float(hb);
            if (k == 0)      { gv0 = vv; gr0 = rr; }
            else if (k == 1) { gv1 = vv; gr1 = rr; }
            else             { gv2 = vv; gr2 = rr; }
            if (p0 == m) { p0 = p1; p1 = p2; p2 = ~0ULL; }   // unique owner
        }

        if (lane == 0) {   // weights: identical formula to passing rounds
            const int qid = b * N_Q + q0 + qi;
            const int i0 = sidx[b * M_PT + gr0];
            const int i1 = sidx[b * M_PT + gr1];
            const int i2 = sidx[b * M_PT + gr2];
            const float rr0 = 1.f / ((gv0 + n1q) + 1e-8f);
            const float rr1 = 1.f / ((gv1 + n1q) + 1e-8f);
            const float rr2 = 1.f / ((gv2 + n1q) + 1e-8f);
            const float rs  = 1.f / (rr0 + rr1 + rr2);
            w4[qid]    = make_float4(rr0 * rs, rr1 * rs, rr2 * rs, 0.f);
            gidx4[qid] = make_int4(i0, i1, i2, 0);
        }
    }
}

// ---------------------------------------------------------------------------
// bf16 MFMA GEMM (m97 structure), optional fused BN-stats partials.
// C stride is H_OUT=256 for all uses (Z, y2).  grid = (rows/128)*2.
// ---------------------------------------------------------------------------
template <int K, bool STATS>
__global__ __launch_bounds__(256, 2) void gemm_bt(const __bf16* __restrict__ A,
                                                  const __bf16* __restrict__ Bw,
                                                  __bf16* __restrict__ Cout,
                                                  float* __restrict__ partS,
                                                  float* __restrict__ partQ) {
    __shared__ __attribute__((aligned(16))) __bf16 As[128 * 32];
    __shared__ __attribute__((aligned(16))) __bf16 Bs[128 * 32];
    const int tid  = threadIdx.x;
    const int wave = tid >> 6, lane = tid & 63;
    const int wm = wave >> 1, wn = wave & 1;
    const int quad = lane >> 4, r16 = lane & 15;
    const int bx = blockIdx.x & 1, by = blockIdx.x >> 1;
    const int l4 = lane >> 2, lk = (lane & 3) * 8;

    f32x4 acc[4][4] = {};

    const __bf16* gA = A  + (size_t)(by * 128 + wave * 32 + l4) * K + lk;
    const __bf16* gB = Bw + (size_t)(bx * 128 + wave * 32 + l4) * K + lk;
    char* lA = (char*)As + wave * 2048;
    char* lB = (char*)Bs + wave * 2048;

    for (int k0 = 0; k0 < K; k0 += 32) {
        async_copy16(gA + k0,                  lA);
        async_copy16(gA + k0 + (size_t)16 * K, lA + 1024);
        async_copy16(gB + k0,                  lB);
        async_copy16(gB + k0 + (size_t)16 * K, lB + 1024);
        __syncthreads();

        bf16x8 af[4], bf[4];
#pragma unroll
        for (int t = 0; t < 4; ++t)
            af[t] = *(const bf16x8*)(As + (wm * 64 + t * 16 + r16) * 32 + quad * 8);
#pragma unroll
        for (int u = 0; u < 4; ++u)
            bf[u] = *(const bf16x8*)(Bs + (wn * 64 + u * 16 + r16) * 32 + quad * 8);
#pragma unroll
        for (int t = 0; t < 4; ++t)
#pragma unroll
            for (int u = 0; u < 4; ++u)
                acc[t][u] = __builtin_amdgcn_mfma_f32_16x16x32_bf16(af[t], bf[u], acc[t][u], 0, 0, 0);
        __syncthreads();
    }

    // C/D layout col=lane&15, row=(lane>>4)*4+reg [m89-verified]
#pragma unroll
    for (int t = 0; t < 4; ++t) {
#pragma unroll
        for (int u = 0; u < 4; ++u) {
            const int col = bx * 128 + wn * 64 + u * 16 + r16;
#pragma unroll
            for (int r = 0; r < 4; ++r) {
                const int row = by * 128 + wm * 64 + t * 16 + quad * 4 + r;
                Cout[(size_t)row * H_OUT + col] = (__bf16)acc[t][u][r];
            }
        }
    }

    if constexpr (STATS) {
        float* redS = (float*)As;          // [col(128)][slot(8)]
        float* redQ = ((float*)As) + 1024;
        const int slot = wm * 4 + quad;
#pragma unroll
        for (int u = 0; u < 4; ++u) {
            float s = 0.f, qq = 0.f;
#pragma unroll
            for (int t = 0; t < 4; ++t)
#pragma unroll
                for (int r = 0; r < 4; ++r) { float v = acc[t][u][r]; s += v; qq = fmaf(v, v, qq); }
            const int col = wn * 64 + u * 16 + r16;
            redS[col * 8 + slot] = s;
            redQ[col * 8 + slot] = qq;
        }
        __syncthreads();
        if (tid < 128) {
            float s = 0.f, qq = 0.f;
#pragma unroll
            for (int k = 0; k < 8; ++k) { s += redS[tid * 8 + k]; qq += redQ[tid * 8 + k]; }
            partS[(size_t)blockIdx.x * 128 + tid] = s;
            partQ[(size_t)blockIdx.x * 128 + tid] = qq;
        }
    }
}

// ---------------------------------------------------------------------------
// GEMM-A (K=128) + fused interpolation epilogue + BN-stats:
//   y1 = p1b @ wb1a^T + sum_k w_k * Z[idx_k]      (linearity of interp)
// Z rows are L2-resident (8.4 MB); gathers are 16-lane-contiguous 2B loads.
// grid = 512*2 = 1024 blocks of 256.  (idx/w come directly from knn_sweep.)
// ---------------------------------------------------------------------------
__global__ __launch_bounds__(256, 2) void gemm_a_int(
    const __bf16* __restrict__ A,  const __bf16* __restrict__ Bw,
    const __bf16* __restrict__ zb, const int4* __restrict__ gidx4,
    const float4* __restrict__ w4, __bf16* __restrict__ Cout,
    float* __restrict__ partS, float* __restrict__ partQ) {
    constexpr int K = C1;   // 128
    __shared__ __attribute__((aligned(16))) __bf16 As[128 * 32];
    __shared__ __attribute__((aligned(16))) __bf16 Bs[128 * 32];
    const int tid  = threadIdx.x;
    const int wave = tid >> 6, lane = tid & 63;
    const int wm = wave >> 1, wn = wave & 1;
    const int quad = lane >> 4, r16 = lane & 15;
    const int bx = blockIdx.x & 1, by = blockIdx.x >> 1;
    const int l4 = lane >> 2, lk = (lane & 3) * 8;

    f32x4 acc[4][4] = {};

    const __bf16* gA = A  + (size_t)(by * 128 + wave * 32 + l4) * K + lk;
    const __bf16* gB = Bw + (size_t)(bx * 128 + wave * 32 + l4) * K + lk;
    char* lA = (char*)As + wave * 2048;
    char* lB = (char*)Bs + wave * 2048;

    for (int k0 = 0; k0 < K; k0 += 32) {
        async_copy16(gA + k0,                  lA);
        async_copy16(gA + k0 + (size_t)16 * K, lA + 1024);
        async_copy16(gB + k0,                  lB);
        async_copy16(gB + k0 + (size_t)16 * K, lB + 1024);
        __syncthreads();

        bf16x8 af[4], bf[4];
#pragma unroll
        for (int t = 0; t < 4; ++t)
            af[t] = *(const bf16x8*)(As + (wm * 64 + t * 16 + r16) * 32 + quad * 8);
#pragma unroll
        for (int u = 0; u < 4; ++u)
            bf[u] = *(const bf16x8*)(Bs + (wn * 64 + u * 16 + r16) * 32 + quad * 8);
#pragma unroll
        for (int t = 0; t < 4; ++t)
#pragma unroll
            for (int u = 0; u < 4; ++u)
                acc[t][u] = __builtin_amdgcn_mfma_f32_16x16x32_bf16(af[t], bf[u], acc[t][u], 0, 0, 0);
        __syncthreads();
    }

    // stage per-row (idx0..2, w0..2) into As (4 KB of the free 8 KB)
    if (tid < 128) {
        const int q = by * 128 + tid;
        ((int4*)As)[tid * 2]       = gidx4[q];
        ((float4*)As)[tid * 2 + 1] = w4[q];
    }
    __syncthreads();

    // add interpolated Z rows into the accumulators
    const int bbase = (by >> 6) * M_PT;   // 64 row-blocks per batch
#pragma unroll
    for (int t = 0; t < 4; ++t) {
#pragma unroll
        for (int r = 0; r < 4; ++r) {
            const int rl = wm * 64 + t * 16 + quad * 4 + r;   // row-in-block
            const int4   ii = ((const int4*)As)[rl * 2];      // broadcast read
            const float4 ww = ((const float4*)As)[rl * 2 + 1];
            const __bf16* z0 = zb + (size_t)(bbase + ii.x) * H_OUT;
            const __bf16* z1 = zb + (size_t)(bbase + ii.y) * H_OUT;
            const __bf16* z2 = zb + (size_t)(bbase + ii.z) * H_OUT;
#pragma unroll
            for (int u = 0; u < 4; ++u) {
                const int col = bx * 128 + wn * 64 + u * 16 + r16;
                acc[t][u][r] += ww.x * (float)z0[col] + ww.y * (float)z1[col]
                              + ww.z * (float)z2[col];
            }
        }
    }

    // C store (bf16 y1)
#pragma unroll
    for (int t = 0; t < 4; ++t) {
#pragma unroll
        for (int u = 0; u < 4; ++u) {
            const int col = bx * 128 + wn * 64 + u * 16 + r16;
#pragma unroll
            for (int r = 0; r < 4; ++r) {
                const int row = by * 128 + wm * 64 + t * 16 + quad * 4 + r;
                Cout[(size_t)row * H_OUT + col] = (__bf16)acc[t][u][r];
            }
        }
    }

    __syncthreads();   // idx/w reads done before stats overwrite As
    float* redS = (float*)As;
    float* redQ = ((float*)As) + 1024;
    const int slot = wm * 4 + quad;
#pragma unroll
    for (int u = 0; u < 4; ++u) {
        float s = 0.f, qq = 0.f;
#pragma unroll
        for (int t = 0; t < 4; ++t)
#pragma unroll
            for (int r = 0; r < 4; ++r) { float v = acc[t][u][r]; s += v; qq = fmaf(v, v, qq); }
        const int col = wn * 64 + u * 16 + r16;
        redS[col * 8 + slot] = s;
        redQ[col * 8 + slot] = qq;
    }
    __syncthreads();
    if (tid < 128) {
        float s = 0.f, qq = 0.f;
#pragma unroll
        for (int k = 0; k < 8; ++k) { s += redS[tid * 8 + k]; qq += redQ[tid * 8 + k]; }
        partS[(size_t)blockIdx.x * 128 + tid] = s;
        partQ[(size_t)blockIdx.x * 128 + tid] = qq;
    }
}

// ---------------------------------------------------------------------------
// fold per-block partials -> per-channel scale/shift.  One block per channel.
// channel c lives in gemm-blocks bid = p*2 + (c>>7), entry (c&127); p<512.
// ---------------------------------------------------------------------------
__global__ __launch_bounds__(256) void bn_finalize(const float* __restrict__ pS,
                                                   const float* __restrict__ pQ,
                                                   const float* __restrict__ gamma,
                                                   const float* __restrict__ beta,
                                                   float* __restrict__ sc,
                                                   float* __restrict__ sh) {
    __shared__ float rs[256], rq[256];
    const int c = blockIdx.x;
    const int t = threadIdx.x;
    const int half = c >> 7, lo = c & 127;
    const size_t o1 = (size_t)(2 * t + half) * 128 + lo;
    const size_t o2 = (size_t)(2 * (t + 256) + half) * 128 + lo;
    rs[t] = pS[o1] + pS[o2];
    rq[t] = pQ[o1] + pQ[o2];
    __syncthreads();
    for (int k = 128; k > 0; k >>= 1) {
        if (t < k) { rs[t] += rs[t + k]; rq[t] += rq[t + k]; }
        __syncthreads();
    }
    if (t == 0) {
        const float inv = 1.f / (float)R_TOT;
        float mean = rs[0] * inv;
        float var  = rq[0] * inv - mean * mean;
        float a    = gamma[c] * rsqrtf(var + 1e-5f);
        sc[c] = a;
        sh[c] = beta[c] - mean * a;
    }
}

// ---------------------------------------------------------------------------
// apply BN+ReLU in place (bf16, layer-1 intermediate)
// ---------------------------------------------------------------------------
__global__ __launch_bounds__(256) void apply_bf16(__bf16* __restrict__ y,
                                                  const float* __restrict__ sc,
                                                  const float* __restrict__ sh) {
    __shared__ float scs[256], shs[256];
    scs[threadIdx.x] = sc[threadIdx.x];
    shs[threadIdx.x] = sh[threadIdx.x];
    __syncthreads();
    size_t i = ((size_t)blockIdx.x * 256 + threadIdx.x) * 8;
    int c0 = (int)(i & 255);
    bf16x8 v = *(const bf16x8*)(y + i);
#pragma unroll
    for (int e = 0; e < 8; ++e) {
        float f = fmaf((float)v[e], scs[c0 + e], shs[c0 + e]);
        v[e] = (__bf16)fmaxf(f, 0.f);
    }
    *(bf16x8*)(y + i) = v;
}

// ---------------------------------------------------------------------------
// apply BN+ReLU reading bf16 y2, writing fp32 output
// ---------------------------------------------------------------------------
__global__ __launch_bounds__(256) void apply_out(const __bf16* __restrict__ y,
                                                 const float* __restrict__ sc,
                                                 const float* __restrict__ sh,
                                                 float* __restrict__ out) {
    __shared__ float scs[256], shs[256];
    scs[threadIdx.x] = sc[threadIdx.x];
    shs[threadIdx.x] = sh[threadIdx.x];
    __syncthreads();
    size_t i = ((size_t)blockIdx.x * 256 + threadIdx.x) * 8;
    int c0 = (int)(i & 255);
    bf16x8 v = *(const bf16x8*)(y + i);
    f32x4 o0, o1;
#pragma unroll
    for (int e = 0; e < 4; ++e)
        o0[e] = fmaxf(fmaf((float)v[e], scs[c0 + e], shs[c0 + e]), 0.f);
#pragma unroll
    for (int e = 0; e < 4; ++e)
        o1[e] = fmaxf(fmaf((float)v[4 + e], scs[c0 + 4 + e], shs[c0 + 4 + e]), 0.f);
    *(f32x4*)(out + i)     = o0;
    *(f32x4*)(out + i + 4) = o1;
}

// ---------------------------------------------------------------------------
extern "C" void kernel_launch(void* const* d_in, const int* in_sizes, int n_in,
                              void* d_out, int out_size, void* d_ws, size_t ws_size,
                              hipStream_t stream) {
    const float* xyz1 = (const float*)d_in[0];
    const float* xyz2 = (const float*)d_in[1];
    const float* p1   = (const float*)d_in[2];
    const float* p2   = (const float*)d_in[3];
    const float* W1   = (const float*)d_in[4];
    // d_in[5] = b1  (cancels in batch-norm)
    const float* g1   = (const float*)d_in[6];
    const float* be1  = (const float*)d_in[7];
    const float* W2   = (const float*)d_in[8];
    // d_in[9] = b2  (cancels in batch-norm)
    const float* g2   = (const float*)d_in[10];
    const float* be2  = (const float*)d_in[11];
    float* out = (float*)d_out;

    // workspace layout (16B aligned), max ~76.9 MB:
    //   gidx4/spts/sidx/pcdf live in the y2b overlay region (all dead after
    //   gemm_a_int / knn_sweep, before gemm_bt<H_OUT> writes y2b)
    char* ws = (char*)d_ws;
    __bf16* y1b   = (__bf16*)(ws);                     // 33,554,432
    int4*   gidx4 = (int4*)  (ws + 33554432);          //  1,048,576
    float4* spts  = (float4*)(ws + 34603008);          //    262,144
    int*    sidx  = (int*)   (ws + 34865152);          //     65,536
    int*    pcdf  = (int*)   (ws + 34930688);          //      8,192
    __bf16* zb    = (__bf16*)(ws + 41943040);          //  8,388,608
    float4* w4    = (float4*)(ws + 50331648);          //  1,048,576
    __bf16* p2b   = (__bf16*)(ws + 51380224);          //  8,388,608
    __bf16* p1b   = (__bf16*)(ws + 59768832);          // 16,777,216
    __bf16* y2b   = (__bf16*)(ws + 33554432);          // 33,554,432 (overlay)
    __bf16* wb1a  = (__bf16*)(ws + 76546048);          //     65,536
    __bf16* wb1b  = (__bf16*)(ws + 76611584);          //    131,072
    __bf16* wb2   = (__bf16*)(ws + 76742656);          //    131,072
    float*  sc1   = (float*) (ws + 76873728);
    float*  sh1   = sc1 + 256;
    float*  sc2   = sc1 + 512;
    float*  sh2   = sc1 + 768;

    float* partS1 = (float*)d_out;            // d_out dead until apply_out
    float* partQ1 = partS1 + 131072;
    float* partS2 = partS1 + 262144;
    float* partQ2 = partS1 + 393216;

    convert_sort<<<2120, 256, 0, stream>>>(xyz2, p1, p2, W1, W2,
                                           p1b, p2b, wb1a, wb1b, wb2,
                                           spts, sidx, pcdf);
    knn_sweep<<<2048, 256, 0, stream>>>(xyz1, spts, sidx, pcdf, w4, gidx4);

    gemm_bt<C2, false><<<256, 256, 0, stream>>>(p2b, wb1b, zb, nullptr, nullptr);
    gemm_a_int<<<1024, 256, 0, stream>>>(p1b, wb1a, zb, gidx4, w4, y1b,
                                         partS1, partQ1);
    bn_finalize<<<256, 256, 0, stream>>>(partS1, partQ1, g1, be1, sc1, sh1);
    apply_bf16<<<8192, 256, 0, stream>>>(y1b, sc1, sh1);

    gemm_bt<H_OUT, true><<<1024, 256, 0, stream>>>(y1b, wb2, y2b, partS2, partQ2);
    bn_finalize<<<256, 256, 0, stream>>>(partS2, partQ2, g2, be2, sc2, sh2);
    apply_out<<<8192, 256, 0, stream>>>(y2b, sc2, sh2, out);
}

// Round 7
// 339.991 us; speedup vs baseline: 1.4520x; 1.0987x over previous
//
#include <hip/hip_runtime.h>
#include <hip/hip_bf16.h>
#include <stdint.h>

// Problem constants (fixed by setup_inputs)
#define B_SZ  8
#define N_Q   8192
#define M_PT  2048
#define C1    128
#define C2    256
#define CIN   384      // C1 + C2
#define H_OUT 256
#define R_TOT 65536    // B_SZ * N_Q

typedef __bf16 bf16x8 __attribute__((ext_vector_type(8)));
typedef __bf16 bf16x4 __attribute__((ext_vector_type(4)));
typedef float  f32x4  __attribute__((ext_vector_type(4)));

// Async global->LDS, 16B per lane. LDS dest is wave-uniform base + lane*16.
__device__ __forceinline__ void async_copy16(const void* g, void* l) {
    __builtin_amdgcn_global_load_lds(
        (const __attribute__((address_space(1))) unsigned int*)g,
        (__attribute__((address_space(3))) unsigned int*)l,
        16, 0, 0);
}

__device__ __forceinline__ unsigned long long shfl_xor64(unsigned long long v,
                                                         int s) {
    const unsigned lo = (unsigned)v, hi = (unsigned)(v >> 32);
    const unsigned ol = __shfl_xor(lo, s), oh = __shfl_xor(hi, s);
    return ((unsigned long long)oh << 32) | ol;
}

// ---------------------------------------------------------------------------
// K1: per-batch x-sort of xyz2 (rank-by-count O(M^2)) + per-batch 256-bin
// x-CDF + W1/W2 converts.  (p1/p2 converts moved into knn_sweep, whose VALU-
// bound blocks hide the streaming.)  Grid = 64 + 8 + 640 = 712 blocks.
// spts[b][rank] = (-2x, -2y, -2z, |p|^2)   (d' operands, bitwise-identical
//                                           to the round-2..6 passing kernels)
// sidx[b][rank] = original point index
// pcdf[b][k]    = first sorted rank in x-bin k
// ---------------------------------------------------------------------------
__global__ __launch_bounds__(256) void convert_sort(
    const float* __restrict__ xyz2, const float* __restrict__ W1,
    const float* __restrict__ W2,
    __bf16* __restrict__ wb1a, __bf16* __restrict__ wb1b,
    __bf16* __restrict__ wb2,  float4* __restrict__ spts,
    int* __restrict__ sidx,    int* __restrict__ pcdf) {
    const int tid = threadIdx.x;

    if (blockIdx.x < 64) {   // ---- point-sort blocks: (b, chunk-of-256)
        __shared__ __attribute__((aligned(16))) float xs[M_PT];
        const int b  = blockIdx.x >> 3;
        const int ch = blockIdx.x & 7;
        const float* x2 = xyz2 + (size_t)b * M_PT * 3;
#pragma unroll
        for (int j = tid; j < M_PT; j += 256) xs[j] = x2[j * 3];
        __syncthreads();
        const int   i  = ch * 256 + tid;
        const float xi = xs[i];
        const float yi = x2[i * 3 + 1], zi = x2[i * 3 + 2];
        int rank = 0;
#pragma unroll 4
        for (int j = 0; j < M_PT; j += 4) {
            const float4 xv = *(const float4*)&xs[j];
            rank += (xv.x < xi || (xv.x == xi && (j + 0) < i)) ? 1 : 0;
            rank += (xv.y < xi || (xv.y == xi && (j + 1) < i)) ? 1 : 0;
            rank += (xv.z < xi || (xv.z == xi && (j + 2) < i)) ? 1 : 0;
            rank += (xv.w < xi || (xv.w == xi && (j + 3) < i)) ? 1 : 0;
        }
        const float pw = fmaf(xi, xi, fmaf(yi, yi, zi * zi));
        spts[(size_t)b * M_PT + rank] =
            make_float4(-2.f * xi, -2.f * yi, -2.f * zi, pw);
        sidx[(size_t)b * M_PT + rank] = i;
        return;
    }

    if (blockIdx.x < 72) {   // ---- point-CDF blocks: one per batch
        __shared__ int hist[256], offs[256];
        const int b = blockIdx.x - 64;
        const float* x2 = xyz2 + (size_t)b * M_PT * 3;
        hist[tid] = 0;
        __syncthreads();
#pragma unroll
        for (int j = tid; j < M_PT; j += 256) {
            const float x = x2[j * 3];
            int bin = (int)((x + 4.0f) * 32.0f);
            bin = min(max(bin, 0), 255);
            atomicAdd(&hist[bin], 1);
        }
        __syncthreads();
        offs[tid] = hist[tid];
        __syncthreads();
        for (int s = 1; s < 256; s <<= 1) {     // inclusive Hillis-Steele
            const int v = (tid >= s) ? offs[tid - s] : 0;
            __syncthreads();
            offs[tid] += v;
            __syncthreads();
        }
        pcdf[b * 256 + tid] = offs[tid] - hist[tid];   // exclusive scan
        return;
    }

    // ---- W-convert blocks: cb in [0, 640)
    const int cb  = blockIdx.x - 72;
    const int gid = cb * 256 + tid;
    if (cb < 384) {                              // W1 split (98304 elems)
        const int e = gid;
        const int o = e / 384, k = e - o * 384;
        __bf16 v = (__bf16)W1[e];
        if (k < C1) wb1a[o * C1 + k] = v;
        else        wb1b[o * C2 + (k - C1)] = v;
    } else {                                     // W2 (65536 elems)
        const int e = gid - 98304;
        wb2[e] = (__bf16)W2[e];
    }
}

// ---------------------------------------------------------------------------
// K2: wave-cooperative sweep KNN, v3 (phase/refresh structure).
// One query per wave at a time (8 per wave); lanes 0..31 sweep left, 32..63
// right, 32 consecutive ranks per side per iteration (conflict-free).  Lane
// keeps a LOCAL top-3 (value+rank); global top-3 c= union of local top-3s.
// CHANGES vs round-6 (which overscanned ~3x: min-of-lane-local-v2 converges
// to ~the 96th-NN distance because best points spread round-robin):
//  * NO cross-lane ops in the scan loop.  Phases of 4 (then 8) iterations;
//    per-iteration stop checks are wave-uniform frontier-bound vs thr.
//  * at each phase boundary: CHEAP value-only exact-merged v2 (3x 6-step
//    fp32 fmin butterfly + tie-evict; tie loss only raises thr => sound)
//    -> thr = gv2 + |q|^2 + 1e-3: the TRUE slab bound, ~290 pts typical.
//  * FULL u64 (value,rank) extraction (round-6 code) runs once, when both
//    sides are done -- it IS the final answer.
// Folds: p1->bf16 (16/thread), p2->bf16 (8/thread) -- streaming hides under
// the VALU-bound scan (grid 2048x256 = 524288 threads matches exactly).
// Block = 4 waves; each wave serves 8 queries; grid = 2048 (4 blocks/CU).
// ---------------------------------------------------------------------------
__global__ __launch_bounds__(256) void knn_sweep(
    const float* __restrict__ xyz1, const float4* __restrict__ spts,
    const int* __restrict__ sidx,   const int* __restrict__ pcdf,
    const float* __restrict__ p1,   const float* __restrict__ p2,
    __bf16* __restrict__ p1b,       __bf16* __restrict__ p2b,
    float4* __restrict__ w4, int4* __restrict__ gidx4) {
    __shared__ __attribute__((aligned(16))) float4 pts[M_PT];   // 32 KB
    __shared__ int pc[256];
    const int tid  = threadIdx.x;
    const int b    = blockIdx.x >> 8;        // 256 blocks per batch
    const int qc   = blockIdx.x & 255;       // 32 queries per block
    const int wave = tid >> 6, lane = tid & 63;

    {   // stage spts[b] (2048 float4) into LDS, async 16B per lane
        const float4* src = spts + (size_t)b * M_PT;
#pragma unroll
        for (int j = 0; j < 8; ++j)
            async_copy16(src + j * 256 + wave * 64 + lane,
                         (char*)pts + ((j * 256 + wave * 64) << 4));
    }
    pc[tid] = pcdf[b * 256 + tid];

    {   // fold: p2 -> bf16 (8/thread) + p1 -> bf16 (16/thread)
        const int gid = blockIdx.x * 256 + tid;       // 0..524287
        const float4* s2 = (const float4*)p2 + (size_t)gid * 2;
        float4 a = s2[0], bb = s2[1];
        bf16x8 o2;
        o2[0]=(__bf16)a.x; o2[1]=(__bf16)a.y; o2[2]=(__bf16)a.z; o2[3]=(__bf16)a.w;
        o2[4]=(__bf16)bb.x; o2[5]=(__bf16)bb.y; o2[6]=(__bf16)bb.z; o2[7]=(__bf16)bb.w;
        *(bf16x8*)(p2b + (size_t)gid * 8) = o2;
        const float4* s1 = (const float4*)p1 + (size_t)gid * 4;
        float4 c0 = s1[0], c1 = s1[1], c2 = s1[2], c3 = s1[3];
        bf16x8 o0, o1;
        o0[0]=(__bf16)c0.x; o0[1]=(__bf16)c0.y; o0[2]=(__bf16)c0.z; o0[3]=(__bf16)c0.w;
        o0[4]=(__bf16)c1.x; o0[5]=(__bf16)c1.y; o0[6]=(__bf16)c1.z; o0[7]=(__bf16)c1.w;
        o1[0]=(__bf16)c2.x; o1[1]=(__bf16)c2.y; o1[2]=(__bf16)c2.z; o1[3]=(__bf16)c2.w;
        o1[4]=(__bf16)c3.x; o1[5]=(__bf16)c3.y; o1[6]=(__bf16)c3.z; o1[7]=(__bf16)c3.w;
        *(bf16x8*)(p1b + (size_t)gid * 16)     = o0;
        *(bf16x8*)(p1b + (size_t)gid * 16 + 8) = o1;
    }
    __syncthreads();

    // preload this wave's 8 queries into lanes 0..7
    float xq = 0.f, yq = 0.f, zq = 0.f;
    const int q0 = qc * 32 + wave * 8;
    if (lane < 8) {
        const float* qp = xyz1 + (size_t)(b * N_Q + q0 + lane) * 3;
        xq = qp[0]; yq = qp[1]; zq = qp[2];
    }
    const int side = lane >> 5, o = lane & 31;

#pragma unroll 1
    for (int qi = 0; qi < 8; ++qi) {
        const float qx = __shfl(xq, qi), qy = __shfl(yq, qi),
                    qz = __shfl(zq, qi);
        const float n1q = fmaf(qx, qx, fmaf(qy, qy, qz * qz));
        int kq = (int)((qx + 4.0f) * 32.0f);
        kq = min(max(kq, 0), 255);
        const int lo = pc[kq];

        float v0 = 3.4e38f, v1 = 3.4e38f, v2 = 3.4e38f;
        int   r0 = 0, r1 = 0, r2 = 0;
        int offL = 0, offR = 0;
        bool dl = false, dr = false, fin = false;
        float thr = 3.4e38f;                 // pre-refresh: only exhaustion
        float bl = 0.f, br = 0.f;
        int myr = side ? (lo + o) : (lo - 1 - o);
        float4 pcur = pts[myr & (M_PT - 1)];
        float gv0 = 3.4e38f, gv1 = 3.4e38f, gv2 = 3.4e38f;
        int   gr0 = 0, gr1 = 0, gr2 = 0;

        // full u64 extraction: exact global top-3 (value,rank) from locals
        auto full_extract = [&]() {
            unsigned u0 = __float_as_uint(v0), u1 = __float_as_uint(v1),
                     u2 = __float_as_uint(v2);
            u0 ^= ((unsigned)((int)u0 >> 31)) | 0x80000000u;
            u1 ^= ((unsigned)((int)u1 >> 31)) | 0x80000000u;
            u2 ^= ((unsigned)((int)u2 >> 31)) | 0x80000000u;
            unsigned long long p0 = ((unsigned long long)u0 << 32) | (unsigned)r0;
            unsigned long long p1q = ((unsigned long long)u1 << 32) | (unsigned)r1;
            unsigned long long p2q = ((unsigned long long)u2 << 32) | (unsigned)r2;
#pragma unroll
            for (int k = 0; k < 3; ++k) {
                unsigned long long m = p0;
#pragma unroll
                for (int s = 1; s < 64; s <<= 1) {
                    const unsigned long long t = shfl_xor64(m, s);
                    m = (t < m) ? t : m;
                }
                const int rr = (int)(m & 0xFFFFFFFFu);
                unsigned  hb = (unsigned)(m >> 32);
                hb = (hb & 0x80000000u) ? (hb ^ 0x80000000u) : ~hb;
                const float vv = __uint_as_float(hb);
                if (k == 0)      { gv0 = vv; gr0 = rr; }
                else if (k == 1) { gv1 = vv; gr1 = rr; }
                else             { gv2 = vv; gr2 = rr; }
                if (p0 == m) { p0 = p1q; p1q = p2q; p2q = ~0ULL; }
            }
        };

#pragma unroll 1
        for (int ref = 0; ref < 9 && !fin; ++ref) {
            const int steps = ref ? 8 : 4;
#pragma unroll
            for (int k = 0; k < 8; ++k) {
                if (k < steps && !(dl && dr)) {
                    const bool act = side ? (!dr && myr < M_PT)
                                          : (!dl && myr >= 0);
                    const int rk = myr & (M_PT - 1);
                    float d = fmaf(pcur.x, qx,
                              fmaf(pcur.y, qy, fmaf(pcur.z, qz, pcur.w)));
                    d = act ? d : 3.4e38f;
                    const bool c0 = d < v0, c1 = d < v1, c2 = d < v2;
                    const float n1v = __builtin_amdgcn_fmed3f(d, v0, v1);
                    const float n2v = __builtin_amdgcn_fmed3f(d, v1, v2);
                    r2 = c1 ? r1 : (c2 ? rk : r2);
                    r1 = c0 ? r0 : (c1 ? rk : r1);
                    r0 = c0 ? rk : r0;
                    v0 = fminf(d, v0); v1 = n1v; v2 = n2v;
                    // advance + prefetch
                    offL += dl ? 0 : 32;
                    offR += dr ? 0 : 32;
                    myr  = side ? (lo + offR + o) : (lo - 1 - offL - o);
                    pcur = pts[myr & (M_PT - 1)];
                    // frontier bounds (wave-uniform broadcast reads)
                    const int fL = lo - 1 - offL, fR = lo + offR;
                    const float xl = pts[max(fL, 0)].x;
                    const float xr = pts[min(fR, M_PT - 1)].x;
                    const float tl = fmaxf(fmaf(0.5f, xl, qx), 0.f);
                    const float tr = fmaxf(-fmaf(0.5f, xr, qx), 0.f);
                    bl = (fL >= 0)   ? tl * tl : 3.4e38f;
                    br = (fR < M_PT) ? tr * tr : 3.4e38f;
                    dl = dl || (bl >= thr);
                    dr = dr || (br >= thr);
                }
            }
            if (dl && dr) {
                full_extract();
                fin = true;
            } else {
                // cheap value-only exact-merged v2 (tie-evict => thr >= v2)
                float a0 = v0, a1 = v1, a2 = v2, cv2 = 3.4e38f;
#pragma unroll
                for (int kk = 0; kk < 3; ++kk) {
                    float m = a0;
#pragma unroll
                    for (int s = 1; s < 64; s <<= 1)
                        m = fminf(m, __shfl_xor(m, s));
                    if (kk == 2) cv2 = m;
                    else {
                        const bool e = (a0 == m);
                        a0 = e ? a1 : a0;
                        a1 = e ? a2 : a1;
                        a2 = e ? 3.4e38f : a2;
                    }
                }
                thr = fminf(cv2 + n1q + 1e-3f, 3.0e38f);
                dl = dl || (bl >= thr);
                dr = dr || (br >= thr);
                if (dl && dr) { full_extract(); fin = true; }
            }
        }
        if (!fin) full_extract();    // insurance (unreachable by coverage)

        if (lane == 0) {   // weights: identical formula to passing rounds
            const int qid = b * N_Q + q0 + qi;
            const int i0 = sidx[b * M_PT + gr0];
            const int i1 = sidx[b * M_PT + gr1];
            const int i2 = sidx[b * M_PT + gr2];
            const float rr0 = 1.f / ((gv0 + n1q) + 1e-8f);
            const float rr1 = 1.f / ((gv1 + n1q) + 1e-8f);
            const float rr2 = 1.f / ((gv2 + n1q) + 1e-8f);
            const float rs  = 1.f / (rr0 + rr1 + rr2);
            w4[qid]    = make_float4(rr0 * rs, rr1 * rs, rr2 * rs, 0.f);
            gidx4[qid] = make_int4(i0, i1, i2, 0);
        }
    }
}

// ---------------------------------------------------------------------------
// bf16 MFMA GEMM (m97 structure), optional fused BN-stats partials.
// C stride is H_OUT=256 for all uses (Z, y2).  grid = (rows/128)*2.
// ---------------------------------------------------------------------------
template <int K, bool STATS>
__global__ __launch_bounds__(256, 2) void gemm_bt(const __bf16* __restrict__ A,
                                                  const __bf16* __restrict__ Bw,
                                                  __bf16* __restrict__ Cout,
                                                  float* __restrict__ partS,
                                                  float* __restrict__ partQ) {
    __shared__ __attribute__((aligned(16))) __bf16 As[128 * 32];
    __shared__ __attribute__((aligned(16))) __bf16 Bs[128 * 32];
    const int tid  = threadIdx.x;
    const int wave = tid >> 6, lane = tid & 63;
    const int wm = wave >> 1, wn = wave & 1;
    const int quad = lane >> 4, r16 = lane & 15;
    const int bx = blockIdx.x & 1, by = blockIdx.x >> 1;
    const int l4 = lane >> 2, lk = (lane & 3) * 8;

    f32x4 acc[4][4] = {};

    const __bf16* gA = A  + (size_t)(by * 128 + wave * 32 + l4) * K + lk;
    const __bf16* gB = Bw + (size_t)(bx * 128 + wave * 32 + l4) * K + lk;
    char* lA = (char*)As + wave * 2048;
    char* lB = (char*)Bs + wave * 2048;

    for (int k0 = 0; k0 < K; k0 += 32) {
        async_copy16(gA + k0,                  lA);
        async_copy16(gA + k0 + (size_t)16 * K, lA + 1024);
        async_copy16(gB + k0,                  lB);
        async_copy16(gB + k0 + (size_t)16 * K, lB + 1024);
        __syncthreads();

        bf16x8 af[4], bf[4];
#pragma unroll
        for (int t = 0; t < 4; ++t)
            af[t] = *(const bf16x8*)(As + (wm * 64 + t * 16 + r16) * 32 + quad * 8);
#pragma unroll
        for (int u = 0; u < 4; ++u)
            bf[u] = *(const bf16x8*)(Bs + (wn * 64 + u * 16 + r16) * 32 + quad * 8);
#pragma unroll
        for (int t = 0; t < 4; ++t)
#pragma unroll
            for (int u = 0; u < 4; ++u)
                acc[t][u] = __builtin_amdgcn_mfma_f32_16x16x32_bf16(af[t], bf[u], acc[t][u], 0, 0, 0);
        __syncthreads();
    }

    // C/D layout col=lane&15, row=(lane>>4)*4+reg [m89-verified]
#pragma unroll
    for (int t = 0; t < 4; ++t) {
#pragma unroll
        for (int u = 0; u < 4; ++u) {
            const int col = bx * 128 + wn * 64 + u * 16 + r16;
#pragma unroll
            for (int r = 0; r < 4; ++r) {
                const int row = by * 128 + wm * 64 + t * 16 + quad * 4 + r;
                Cout[(size_t)row * H_OUT + col] = (__bf16)acc[t][u][r];
            }
        }
    }

    if constexpr (STATS) {
        float* redS = (float*)As;          // [col(128)][slot(8)]
        float* redQ = ((float*)As) + 1024;
        const int slot = wm * 4 + quad;
#pragma unroll
        for (int u = 0; u < 4; ++u) {
            float s = 0.f, qq = 0.f;
#pragma unroll
            for (int t = 0; t < 4; ++t)
#pragma unroll
                for (int r = 0; r < 4; ++r) { float v = acc[t][u][r]; s += v; qq = fmaf(v, v, qq); }
            const int col = wn * 64 + u * 16 + r16;
            redS[col * 8 + slot] = s;
            redQ[col * 8 + slot] = qq;
        }
        __syncthreads();
        if (tid < 128) {
            float s = 0.f, qq = 0.f;
#pragma unroll
            for (int k = 0; k < 8; ++k) { s += redS[tid * 8 + k]; qq += redQ[tid * 8 + k]; }
            partS[(size_t)blockIdx.x * 128 + tid] = s;
            partQ[(size_t)blockIdx.x * 128 + tid] = qq;
        }
    }
}

// ---------------------------------------------------------------------------
// GEMM-A (K=128) + fused interpolation epilogue + BN-stats:
//   y1 = p1b @ wb1a^T + sum_k w_k * Z[idx_k]      (linearity of interp)
// Z rows are L2-resident (8.4 MB); gathers are 16-lane-contiguous 2B loads.
// grid = 512*2 = 1024 blocks of 256.  (idx/w come directly from knn_sweep.)
// ---------------------------------------------------------------------------
__global__ __launch_bounds__(256, 2) void gemm_a_int(
    const __bf16* __restrict__ A,  const __bf16* __restrict__ Bw,
    const __bf16* __restrict__ zb, const int4* __restrict__ gidx4,
    const float4* __restrict__ w4, __bf16* __restrict__ Cout,
    float* __restrict__ partS, float* __restrict__ partQ) {
    constexpr int K = C1;   // 128
    __shared__ __attribute__((aligned(16))) __bf16 As[128 * 32];
    __shared__ __attribute__((aligned(16))) __bf16 Bs[128 * 32];
    const int tid  = threadIdx.x;
    const int wave = tid >> 6, lane = tid & 63;
    const int wm = wave >> 1, wn = wave & 1;
    const int quad = lane >> 4, r16 = lane & 15;
    const int bx = blockIdx.x & 1, by = blockIdx.x >> 1;
    const int l4 = lane >> 2, lk = (lane & 3) * 8;

    f32x4 acc[4][4] = {};

    const __bf16* gA = A  + (size_t)(by * 128 + wave * 32 + l4) * K + lk;
    const __bf16* gB = Bw + (size_t)(bx * 128 + wave * 32 + l4) * K + lk;
    char* lA = (char*)As + wave * 2048;
    char* lB = (char*)Bs + wave * 2048;

    for (int k0 = 0; k0 < K; k0 += 32) {
        async_copy16(gA + k0,                  lA);
        async_copy16(gA + k0 + (size_t)16 * K, lA + 1024);
        async_copy16(gB + k0,                  lB);
        async_copy16(gB + k0 + (size_t)16 * K, lB + 1024);
        __syncthreads();

        bf16x8 af[4], bf[4];
#pragma unroll
        for (int t = 0; t < 4; ++t)
            af[t] = *(const bf16x8*)(As + (wm * 64 + t * 16 + r16) * 32 + quad * 8);
#pragma unroll
        for (int u = 0; u < 4; ++u)
            bf[u] = *(const bf16x8*)(Bs + (wn * 64 + u * 16 + r16) * 32 + quad * 8);
#pragma unroll
        for (int t = 0; t < 4; ++t)
#pragma unroll
            for (int u = 0; u < 4; ++u)
                acc[t][u] = __builtin_amdgcn_mfma_f32_16x16x32_bf16(af[t], bf[u], acc[t][u], 0, 0, 0);
        __syncthreads();
    }

    // stage per-row (idx0..2, w0..2) into As (4 KB of the free 8 KB)
    if (tid < 128) {
        const int q = by * 128 + tid;
        ((int4*)As)[tid * 2]       = gidx4[q];
        ((float4*)As)[tid * 2 + 1] = w4[q];
    }
    __syncthreads();

    // add interpolated Z rows into the accumulators
    const int bbase = (by >> 6) * M_PT;   // 64 row-blocks per batch
#pragma unroll
    for (int t = 0; t < 4; ++t) {
#pragma unroll
        for (int r = 0; r < 4; ++r) {
            const int rl = wm * 64 + t * 16 + quad * 4 + r;   // row-in-block
            const int4   ii = ((const int4*)As)[rl * 2];      // broadcast read
            const float4 ww = ((const float4*)As)[rl * 2 + 1];
            const __bf16* z0 = zb + (size_t)(bbase + ii.x) * H_OUT;
            const __bf16* z1 = zb + (size_t)(bbase + ii.y) * H_OUT;
            const __bf16* z2 = zb + (size_t)(bbase + ii.z) * H_OUT;
#pragma unroll
            for (int u = 0; u < 4; ++u) {
                const int col = bx * 128 + wn * 64 + u * 16 + r16;
                acc[t][u][r] += ww.x * (float)z0[col] + ww.y * (float)z1[col]
                              + ww.z * (float)z2[col];
            }
        }
    }

    // C store (bf16 y1)
#pragma unroll
    for (int t = 0; t < 4; ++t) {
#pragma unroll
        for (int u = 0; u < 4; ++u) {
            const int col = bx * 128 + wn * 64 + u * 16 + r16;
#pragma unroll
            for (int r = 0; r < 4; ++r) {
                const int row = by * 128 + wm * 64 + t * 16 + quad * 4 + r;
                Cout[(size_t)row * H_OUT + col] = (__bf16)acc[t][u][r];
            }
        }
    }

    __syncthreads();   // idx/w reads done before stats overwrite As
    float* redS = (float*)As;
    float* redQ = ((float*)As) + 1024;
    const int slot = wm * 4 + quad;
#pragma unroll
    for (int u = 0; u < 4; ++u) {
        float s = 0.f, qq = 0.f;
#pragma unroll
        for (int t = 0; t < 4; ++t)
#pragma unroll
            for (int r = 0; r < 4; ++r) { float v = acc[t][u][r]; s += v; qq = fmaf(v, v, qq); }
        const int col = wn * 64 + u * 16 + r16;
        redS[col * 8 + slot] = s;
        redQ[col * 8 + slot] = qq;
    }
    __syncthreads();
    if (tid < 128) {
        float s = 0.f, qq = 0.f;
#pragma unroll
        for (int k = 0; k < 8; ++k) { s += redS[tid * 8 + k]; qq += redQ[tid * 8 + k]; }
        partS[(size_t)blockIdx.x * 128 + tid] = s;
        partQ[(size_t)blockIdx.x * 128 + tid] = qq;
    }
}

// ---------------------------------------------------------------------------
// fold per-block partials -> per-channel scale/shift.  One block per channel.
// channel c lives in gemm-blocks bid = p*2 + (c>>7), entry (c&127); p<512.
// ---------------------------------------------------------------------------
__global__ __launch_bounds__(256) void bn_finalize(const float* __restrict__ pS,
                                                   const float* __restrict__ pQ,
                                                   const float* __restrict__ gamma,
                                                   const float* __restrict__ beta,
                                                   float* __restrict__ sc,
                                                   float* __restrict__ sh) {
    __shared__ float rs[256], rq[256];
    const int c = blockIdx.x;
    const int t = threadIdx.x;
    const int half = c >> 7, lo = c & 127;
    const size_t o1 = (size_t)(2 * t + half) * 128 + lo;
    const size_t o2 = (size_t)(2 * (t + 256) + half) * 128 + lo;
    rs[t] = pS[o1] + pS[o2];
    rq[t] = pQ[o1] + pQ[o2];
    __syncthreads();
    for (int k = 128; k > 0; k >>= 1) {
        if (t < k) { rs[t] += rs[t + k]; rq[t] += rq[t + k]; }
        __syncthreads();
    }
    if (t == 0) {
        const float inv = 1.f / (float)R_TOT;
        float mean = rs[0] * inv;
        float var  = rq[0] * inv - mean * mean;
        float a    = gamma[c] * rsqrtf(var + 1e-5f);
        sc[c] = a;
        sh[c] = beta[c] - mean * a;
    }
}

// ---------------------------------------------------------------------------
// apply BN+ReLU in place (bf16, layer-1 intermediate)
// ---------------------------------------------------------------------------
__global__ __launch_bounds__(256) void apply_bf16(__bf16* __restrict__ y,
                                                  const float* __restrict__ sc,
                                                  const float* __restrict__ sh) {
    __shared__ float scs[256], shs[256];
    scs[threadIdx.x] = sc[threadIdx.x];
    shs[threadIdx.x] = sh[threadIdx.x];
    __syncthreads();
    size_t i = ((size_t)blockIdx.x * 256 + threadIdx.x) * 8;
    int c0 = (int)(i & 255);
    bf16x8 v = *(const bf16x8*)(y + i);
#pragma unroll
    for (int e = 0; e < 8; ++e) {
        float f = fmaf((float)v[e], scs[c0 + e], shs[c0 + e]);
        v[e] = (__bf16)fmaxf(f, 0.f);
    }
    *(bf16x8*)(y + i) = v;
}

// ---------------------------------------------------------------------------
// apply BN+ReLU reading bf16 y2, writing fp32 output
// ---------------------------------------------------------------------------
__global__ __launch_bounds__(256) void apply_out(const __bf16* __restrict__ y,
                                                 const float* __restrict__ sc,
                                                 const float* __restrict__ sh,
                                                 float* __restrict__ out) {
    __shared__ float scs[256], shs[256];
    scs[threadIdx.x] = sc[threadIdx.x];
    shs[threadIdx.x] = sh[threadIdx.x];
    __syncthreads();
    size_t i = ((size_t)blockIdx.x * 256 + threadIdx.x) * 8;
    int c0 = (int)(i & 255);
    bf16x8 v = *(const bf16x8*)(y + i);
    f32x4 o0, o1;
#pragma unroll
    for (int e = 0; e < 4; ++e)
        o0[e] = fmaxf(fmaf((float)v[e], scs[c0 + e], shs[c0 + e]), 0.f);
#pragma unroll
    for (int e = 0; e < 4; ++e)
        o1[e] = fmaxf(fmaf((float)v[4 + e], scs[c0 + 4 + e], shs[c0 + 4 + e]), 0.f);
    *(f32x4*)(out + i)     = o0;
    *(f32x4*)(out + i + 4) = o1;
}

// ---------------------------------------------------------------------------
extern "C" void kernel_launch(void* const* d_in, const int* in_sizes, int n_in,
                              void* d_out, int out_size, void* d_ws, size_t ws_size,
                              hipStream_t stream) {
    const float* xyz1 = (const float*)d_in[0];
    const float* xyz2 = (const float*)d_in[1];
    const float* p1   = (const float*)d_in[2];
    const float* p2   = (const float*)d_in[3];
    const float* W1   = (const float*)d_in[4];
    // d_in[5] = b1  (cancels in batch-norm)
    const float* g1   = (const float*)d_in[6];
    const float* be1  = (const float*)d_in[7];
    const float* W2   = (const float*)d_in[8];
    // d_in[9] = b2  (cancels in batch-norm)
    const float* g2   = (const float*)d_in[10];
    const float* be2  = (const float*)d_in[11];
    float* out = (float*)d_out;

    // workspace layout (16B aligned), max ~76.9 MB:
    //   gidx4/spts/sidx/pcdf live in the y2b overlay region (all dead after
    //   gemm_a_int / knn_sweep, before gemm_bt<H_OUT> writes y2b)
    char* ws = (char*)d_ws;
    __bf16* y1b   = (__bf16*)(ws);                     // 33,554,432
    int4*   gidx4 = (int4*)  (ws + 33554432);          //  1,048,576
    float4* spts  = (float4*)(ws + 34603008);          //    262,144
    int*    sidx  = (int*)   (ws + 34865152);          //     65,536
    int*    pcdf  = (int*)   (ws + 34930688);          //      8,192
    __bf16* zb    = (__bf16*)(ws + 41943040);          //  8,388,608
    float4* w4    = (float4*)(ws + 50331648);          //  1,048,576
    __bf16* p2b   = (__bf16*)(ws + 51380224);          //  8,388,608
    __bf16* p1b   = (__bf16*)(ws + 59768832);          // 16,777,216
    __bf16* y2b   = (__bf16*)(ws + 33554432);          // 33,554,432 (overlay)
    __bf16* wb1a  = (__bf16*)(ws + 76546048);          //     65,536
    __bf16* wb1b  = (__bf16*)(ws + 76611584);          //    131,072
    __bf16* wb2   = (__bf16*)(ws + 76742656);          //    131,072
    float*  sc1   = (float*) (ws + 76873728);
    float*  sh1   = sc1 + 256;
    float*  sc2   = sc1 + 512;
    float*  sh2   = sc1 + 768;

    float* partS1 = (float*)d_out;            // d_out dead until apply_out
    float* partQ1 = partS1 + 131072;
    float* partS2 = partS1 + 262144;
    float* partQ2 = partS1 + 393216;

    convert_sort<<<712, 256, 0, stream>>>(xyz2, W1, W2, wb1a, wb1b, wb2,
                                          spts, sidx, pcdf);
    knn_sweep<<<2048, 256, 0, stream>>>(xyz1, spts, sidx, pcdf,
                                        p1, p2, p1b, p2b, w4, gidx4);

    gemm_bt<C2, false><<<256, 256, 0, stream>>>(p2b, wb1b, zb, nullptr, nullptr);
    gemm_a_int<<<1024, 256, 0, stream>>>(p1b, wb1a, zb, gidx4, w4, y1b,
                                         partS1, partQ1);
    bn_finalize<<<256, 256, 0, stream>>>(partS1, partQ1, g1, be1, sc1, sh1);
    apply_bf16<<<8192, 256, 0, stream>>>(y1b, sc1, sh1);

    gemm_bt<H_OUT, true><<<1024, 256, 0, stream>>>(y1b, wb2, y2b, partS2, partQ2);
    bn_finalize<<<256, 256, 0, stream>>>(partS2, partQ2, g2, be2, sc2, sh2);
    apply_out<<<8192, 256, 0, stream>>>(y2b, sc2, sh2, out);
}

// Round 8
// 320.365 us; speedup vs baseline: 1.5410x; 1.0613x over previous
//
#include <hip/hip_runtime.h>
#include <hip/hip_bf16.h>
#include <stdint.h>

// Problem constants (fixed by setup_inputs)
#define B_SZ  8
#define N_Q   8192
#define M_PT  2048
#define C1    128
#define C2    256
#define CIN   384      // C1 + C2
#define H_OUT 256
#define R_TOT 65536    // B_SZ * N_Q

typedef __bf16 bf16x8 __attribute__((ext_vector_type(8)));
typedef __bf16 bf16x4 __attribute__((ext_vector_type(4)));
typedef float  f32x4  __attribute__((ext_vector_type(4)));

// Async global->LDS, 16B per lane. LDS dest is wave-uniform base + lane*16.
__device__ __forceinline__ void async_copy16(const void* g, void* l) {
    __builtin_amdgcn_global_load_lds(
        (const __attribute__((address_space(1))) unsigned int*)g,
        (__attribute__((address_space(3))) unsigned int*)l,
        16, 0, 0);
}

__device__ __forceinline__ unsigned long long shfl_xor64(unsigned long long v,
                                                         int s) {
    const unsigned lo = (unsigned)v, hi = (unsigned)(v >> 32);
    const unsigned ol = __shfl_xor(lo, s), oh = __shfl_xor(hi, s);
    return ((unsigned long long)oh << 32) | ol;
}
__device__ __forceinline__ unsigned long long umin64(unsigned long long a,
                                                     unsigned long long b) {
    return a < b ? a : b;
}
__device__ __forceinline__ unsigned long long umax64(unsigned long long a,
                                                     unsigned long long b) {
    return a > b ? a : b;
}

// ---------------------------------------------------------------------------
// K1: per-batch x-sort of xyz2 (rank-by-count O(M^2)) + per-batch 256-bin
// x-CDF + W1/W2 converts.  (p1/p2 converts live in knn_sweep, whose VALU-
// bound blocks hide the streaming.)  Grid = 64 + 8 + 640 = 712 blocks.
// spts[b][rank] = (-2x, -2y, -2z, |p|^2)   (d' operands, bitwise-identical
//                                           to the round-2..7 passing kernels)
// sidx[b][rank] = original point index
// pcdf[b][k]    = first sorted rank in x-bin k
// ---------------------------------------------------------------------------
__global__ __launch_bounds__(256) void convert_sort(
    const float* __restrict__ xyz2, const float* __restrict__ W1,
    const float* __restrict__ W2,
    __bf16* __restrict__ wb1a, __bf16* __restrict__ wb1b,
    __bf16* __restrict__ wb2,  float4* __restrict__ spts,
    int* __restrict__ sidx,    int* __restrict__ pcdf) {
    const int tid = threadIdx.x;

    if (blockIdx.x < 64) {   // ---- point-sort blocks: (b, chunk-of-256)
        __shared__ __attribute__((aligned(16))) float xs[M_PT];
        const int b  = blockIdx.x >> 3;
        const int ch = blockIdx.x & 7;
        const float* x2 = xyz2 + (size_t)b * M_PT * 3;
#pragma unroll
        for (int j = tid; j < M_PT; j += 256) xs[j] = x2[j * 3];
        __syncthreads();
        const int   i  = ch * 256 + tid;
        const float xi = xs[i];
        const float yi = x2[i * 3 + 1], zi = x2[i * 3 + 2];
        int rank = 0;
#pragma unroll 4
        for (int j = 0; j < M_PT; j += 4) {
            const float4 xv = *(const float4*)&xs[j];
            rank += (xv.x < xi || (xv.x == xi && (j + 0) < i)) ? 1 : 0;
            rank += (xv.y < xi || (xv.y == xi && (j + 1) < i)) ? 1 : 0;
            rank += (xv.z < xi || (xv.z == xi && (j + 2) < i)) ? 1 : 0;
            rank += (xv.w < xi || (xv.w == xi && (j + 3) < i)) ? 1 : 0;
        }
        const float pw = fmaf(xi, xi, fmaf(yi, yi, zi * zi));
        spts[(size_t)b * M_PT + rank] =
            make_float4(-2.f * xi, -2.f * yi, -2.f * zi, pw);
        sidx[(size_t)b * M_PT + rank] = i;
        return;
    }

    if (blockIdx.x < 72) {   // ---- point-CDF blocks: one per batch
        __shared__ int hist[256], offs[256];
        const int b = blockIdx.x - 64;
        const float* x2 = xyz2 + (size_t)b * M_PT * 3;
        hist[tid] = 0;
        __syncthreads();
#pragma unroll
        for (int j = tid; j < M_PT; j += 256) {
            const float x = x2[j * 3];
            int bin = (int)((x + 4.0f) * 32.0f);
            bin = min(max(bin, 0), 255);
            atomicAdd(&hist[bin], 1);
        }
        __syncthreads();
        offs[tid] = hist[tid];
        __syncthreads();
        for (int s = 1; s < 256; s <<= 1) {     // inclusive Hillis-Steele
            const int v = (tid >= s) ? offs[tid - s] : 0;
            __syncthreads();
            offs[tid] += v;
            __syncthreads();
        }
        pcdf[b * 256 + tid] = offs[tid] - hist[tid];   // exclusive scan
        return;
    }

    // ---- W-convert blocks: cb in [0, 640)
    const int cb  = blockIdx.x - 72;
    const int gid = cb * 256 + tid;
    if (cb < 384) {                              // W1 split (98304 elems)
        const int e = gid;
        const int o = e / 384, k = e - o * 384;
        __bf16 v = (__bf16)W1[e];
        if (k < C1) wb1a[o * C1 + k] = v;
        else        wb1b[o * C2 + (k - C1)] = v;
    } else {                                     // W2 (65536 elems)
        const int e = gid - 98304;
        wb2[e] = (__bf16)W2[e];
    }
}

// ---------------------------------------------------------------------------
// K2: wave-cooperative sweep KNN, v4 (single merge-reduce structure).
// One query per wave (8 serially); lanes 0..31 sweep left, 32..63 right,
// 32 consecutive ranks/side/iteration (conflict-free).  Lane keeps a LOCAL
// sorted top-3 (value+rank); global top-3 c= union of lane-local top-3s.
// CHANGES vs round-7 (whose cost was dominated by ~2000cy/query of
// SEQUENTIAL cross-lane chains: 3x6-step cheap refresh + 3x6-step extract):
//  * ONE 6-step butterfly that merges sorted (value,rank)-packed u64 TRIPLES
//    (min/max/med3 network keeps the 3 smallest per step; formula verified
//    by case enumeration).  One pass = exact global top-3 WITH ranks.
//  * Phase A: 6 fixed iterations (384 pts, covers most slabs) with minimal
//    body (single unsigned bounds-cmp, unconditional advance, no frontier
//    checks).  Then merge-reduce #1 -> thr = gv2 + |q|^2 + 1e-3 (exact slab
//    bound).  If frontier bounds not met: Phase B = round-7-style checked
//    iterations (thr fixed; only-larger => sound) then merge-reduce #2.
//  * queries staged in LDS (broadcast read) instead of 3 shfls each.
// Folds: p1->bf16 (16/thread), p2->bf16 (8/thread) hide under VALU scan.
// Block = 4 waves; each wave serves 8 queries; grid = 2048 (4 blocks/CU).
// ---------------------------------------------------------------------------
__global__ __launch_bounds__(256) void knn_sweep(
    const float* __restrict__ xyz1, const float4* __restrict__ spts,
    const int* __restrict__ sidx,   const int* __restrict__ pcdf,
    const float* __restrict__ p1,   const float* __restrict__ p2,
    __bf16* __restrict__ p1b,       __bf16* __restrict__ p2b,
    float4* __restrict__ w4, int4* __restrict__ gidx4) {
    __shared__ __attribute__((aligned(16))) float4 pts[M_PT];   // 32 KB
    __shared__ int pc[256];
    __shared__ __attribute__((aligned(16))) float4 qs[32];
    const int tid  = threadIdx.x;
    const int b    = blockIdx.x >> 8;        // 256 blocks per batch
    const int qc   = blockIdx.x & 255;       // 32 queries per block
    const int wave = tid >> 6, lane = tid & 63;

    {   // stage spts[b] (2048 float4) into LDS, async 16B per lane
        const float4* src = spts + (size_t)b * M_PT;
#pragma unroll
        for (int j = 0; j < 8; ++j)
            async_copy16(src + j * 256 + wave * 64 + lane,
                         (char*)pts + ((j * 256 + wave * 64) << 4));
    }
    pc[tid] = pcdf[b * 256 + tid];
    if (tid < 32) {   // stage this block's 32 queries
        const float* qp = xyz1 + (size_t)(b * N_Q + qc * 32 + tid) * 3;
        qs[tid] = make_float4(qp[0], qp[1], qp[2], 0.f);
    }

    {   // fold: p2 -> bf16 (8/thread) + p1 -> bf16 (16/thread)
        const int gid = blockIdx.x * 256 + tid;       // 0..524287
        const float4* s2 = (const float4*)p2 + (size_t)gid * 2;
        float4 a = s2[0], bb = s2[1];
        bf16x8 o2;
        o2[0]=(__bf16)a.x; o2[1]=(__bf16)a.y; o2[2]=(__bf16)a.z; o2[3]=(__bf16)a.w;
        o2[4]=(__bf16)bb.x; o2[5]=(__bf16)bb.y; o2[6]=(__bf16)bb.z; o2[7]=(__bf16)bb.w;
        *(bf16x8*)(p2b + (size_t)gid * 8) = o2;
        const float4* s1 = (const float4*)p1 + (size_t)gid * 4;
        float4 c0 = s1[0], c1 = s1[1], c2 = s1[2], c3 = s1[3];
        bf16x8 o0, o1;
        o0[0]=(__bf16)c0.x; o0[1]=(__bf16)c0.y; o0[2]=(__bf16)c0.z; o0[3]=(__bf16)c0.w;
        o0[4]=(__bf16)c1.x; o0[5]=(__bf16)c1.y; o0[6]=(__bf16)c1.z; o0[7]=(__bf16)c1.w;
        o1[0]=(__bf16)c2.x; o1[1]=(__bf16)c2.y; o1[2]=(__bf16)c2.z; o1[3]=(__bf16)c2.w;
        o1[4]=(__bf16)c3.x; o1[5]=(__bf16)c3.y; o1[6]=(__bf16)c3.z; o1[7]=(__bf16)c3.w;
        *(bf16x8*)(p1b + (size_t)gid * 16)     = o0;
        *(bf16x8*)(p1b + (size_t)gid * 16 + 8) = o1;
    }
    __syncthreads();

    const int side = lane >> 5, o = lane & 31;
    const int stp  = side ? 32 : -32;

#pragma unroll 1
    for (int qi = 0; qi < 8; ++qi) {
        const float4 qv = qs[wave * 8 + qi];          // broadcast LDS read
        const float qx = qv.x, qy = qv.y, qz = qv.z;
        const float n1q = fmaf(qx, qx, fmaf(qy, qy, qz * qz));
        int kq = (int)((qx + 4.0f) * 32.0f);
        kq = min(max(kq, 0), 255);
        const int lo = pc[kq];

        float v0 = 3.4e38f, v1 = 3.4e38f, v2 = 3.4e38f;
        int   r0 = 0, r1 = 0, r2 = 0;
        int myr = side ? (lo + o) : (lo - 1 - o);
        float4 pcur = pts[myr & (M_PT - 1)];

        // ---- Phase A: 6 fixed iterations, minimal body
#pragma unroll
        for (int it = 0; it < 6; ++it) {
            const bool act = (unsigned)myr < (unsigned)M_PT;  // both sides
            const int rk = myr & (M_PT - 1);
            float d = fmaf(pcur.x, qx,
                      fmaf(pcur.y, qy, fmaf(pcur.z, qz, pcur.w)));
            d = act ? d : 3.4e38f;
            const bool c0 = d < v0, c1 = d < v1, c2 = d < v2;
            const float n1v = __builtin_amdgcn_fmed3f(d, v0, v1);
            const float n2v = __builtin_amdgcn_fmed3f(d, v1, v2);
            r2 = c1 ? r1 : (c2 ? rk : r2);
            r1 = c0 ? r0 : (c1 ? rk : r1);
            r0 = c0 ? rk : r0;
            v0 = fminf(d, v0); v1 = n1v; v2 = n2v;
            myr += stp;
            pcur = pts[myr & (M_PT - 1)];
        }
        int offL = 192, offR = 192;

        // ---- merge-reduce: exact global top-3 (value,rank) in all lanes
        unsigned long long g0, g1, g2;
        auto merge_reduce = [&]() {
            unsigned u0 = __float_as_uint(v0), u1 = __float_as_uint(v1),
                     u2 = __float_as_uint(v2);
            u0 ^= ((unsigned)((int)u0 >> 31)) | 0x80000000u;
            u1 ^= ((unsigned)((int)u1 >> 31)) | 0x80000000u;
            u2 ^= ((unsigned)((int)u2 >> 31)) | 0x80000000u;
            unsigned long long a0 = ((unsigned long long)u0 << 32) | (unsigned)r0;
            unsigned long long a1 = ((unsigned long long)u1 << 32) | (unsigned)r1;
            unsigned long long a2 = ((unsigned long long)u2 << 32) | (unsigned)r2;
#pragma unroll
            for (int s = 1; s < 64; s <<= 1) {
                const unsigned long long b0 = shfl_xor64(a0, s);
                const unsigned long long b1 = shfl_xor64(a1, s);
                const unsigned long long b2 = shfl_xor64(a2, s);
                const unsigned long long t0 = umax64(a0, b0);
                const unsigned long long m1 = umin64(a1, b1);
                const unsigned long long M1 = umax64(a1, b1);
                const unsigned long long m2 = umin64(a2, b2);
                const unsigned long long c0n = umin64(a0, b0);
                const unsigned long long c1n = umin64(t0, m1);
                const unsigned long long T1  = umax64(t0, m1);
                const unsigned long long c2n = umax64(c1n,
                                               umin64(T1, umin64(M1, m2)));
                a0 = c0n; a1 = c1n; a2 = c2n;
            }
            g0 = a0; g1 = a1; g2 = a2;
        };
        merge_reduce();

        // thr from exact gv2; frontier bounds after phase A
        auto unpackv = [](unsigned long long p) -> float {
            unsigned hb = (unsigned)(p >> 32);
            hb = (hb & 0x80000000u) ? (hb ^ 0x80000000u) : ~hb;
            return __uint_as_float(hb);
        };
        const float thr = fminf(unpackv(g2) + n1q + 1e-3f, 3.0e38f);
        {
            const int fL = lo - 1 - offL, fR = lo + offR;
            const float xl = pts[max(fL, 0)].x;
            const float xr = pts[min(fR, M_PT - 1)].x;
            const float tl = fmaxf(fmaf(0.5f, xl, qx), 0.f);
            const float tr = fmaxf(-fmaf(0.5f, xr, qx), 0.f);
            const float bl = (fL >= 0)   ? tl * tl : 3.4e38f;
            const float br = (fR < M_PT) ? tr * tr : 3.4e38f;
            bool dl = bl >= thr, dr = br >= thr;

            if (!(dl && dr)) {   // ---- Phase B (checked iterations)
#pragma unroll 1
                for (int it = 0; it < 60 && !(dl && dr); ++it) {
                    const bool act = side ? (!dr && myr < M_PT)
                                          : (!dl && myr >= 0);
                    const int rk = myr & (M_PT - 1);
                    float d = fmaf(pcur.x, qx,
                              fmaf(pcur.y, qy, fmaf(pcur.z, qz, pcur.w)));
                    d = act ? d : 3.4e38f;
                    const bool c0 = d < v0, c1 = d < v1, c2 = d < v2;
                    const float n1v = __builtin_amdgcn_fmed3f(d, v0, v1);
                    const float n2v = __builtin_amdgcn_fmed3f(d, v1, v2);
                    r2 = c1 ? r1 : (c2 ? rk : r2);
                    r1 = c0 ? r0 : (c1 ? rk : r1);
                    r0 = c0 ? rk : r0;
                    v0 = fminf(d, v0); v1 = n1v; v2 = n2v;
                    offL += dl ? 0 : 32;
                    offR += dr ? 0 : 32;
                    myr  = side ? (lo + offR + o) : (lo - 1 - offL - o);
                    pcur = pts[myr & (M_PT - 1)];
                    const int fL2 = lo - 1 - offL, fR2 = lo + offR;
                    const float xl2 = pts[max(fL2, 0)].x;
                    const float xr2 = pts[min(fR2, M_PT - 1)].x;
                    const float tl2 = fmaxf(fmaf(0.5f, xl2, qx), 0.f);
                    const float tr2 = fmaxf(-fmaf(0.5f, xr2, qx), 0.f);
                    const float bl2 = (fL2 >= 0)   ? tl2 * tl2 : 3.4e38f;
                    const float br2 = (fR2 < M_PT) ? tr2 * tr2 : 3.4e38f;
                    dl = dl || (bl2 >= thr);
                    dr = dr || (br2 >= thr);
                }
                merge_reduce();     // re-extract with phase-B contributions
            }
        }

        if (lane == 0) {   // weights: identical formula to passing rounds
            const float gv0 = unpackv(g0), gv1 = unpackv(g1),
                        gv2 = unpackv(g2);
            const int gr0 = (int)(g0 & 0xFFFFFFFFu);
            const int gr1 = (int)(g1 & 0xFFFFFFFFu);
            const int gr2 = (int)(g2 & 0xFFFFFFFFu);
            const int qid = b * N_Q + qc * 32 + wave * 8 + qi;
            const int i0 = sidx[b * M_PT + gr0];
            const int i1 = sidx[b * M_PT + gr1];
            const int i2 = sidx[b * M_PT + gr2];
            const float rr0 = 1.f / ((gv0 + n1q) + 1e-8f);
            const float rr1 = 1.f / ((gv1 + n1q) + 1e-8f);
            const float rr2 = 1.f / ((gv2 + n1q) + 1e-8f);
            const float rs  = 1.f / (rr0 + rr1 + rr2);
            w4[qid]    = make_float4(rr0 * rs, rr1 * rs, rr2 * rs, 0.f);
            gidx4[qid] = make_int4(i0, i1, i2, 0);
        }
    }
}

// ---------------------------------------------------------------------------
// bf16 MFMA GEMM (m97 structure), optional fused BN-stats partials.
// C stride is H_OUT=256 for all uses (Z, y2).  grid = (rows/128)*2.
// ---------------------------------------------------------------------------
template <int K, bool STATS>
__global__ __launch_bounds__(256, 2) void gemm_bt(const __bf16* __restrict__ A,
                                                  const __bf16* __restrict__ Bw,
                                                  __bf16* __restrict__ Cout,
                                                  float* __restrict__ partS,
                                                  float* __restrict__ partQ) {
    __shared__ __attribute__((aligned(16))) __bf16 As[128 * 32];
    __shared__ __attribute__((aligned(16))) __bf16 Bs[128 * 32];
    const int tid  = threadIdx.x;
    const int wave = tid >> 6, lane = tid & 63;
    const int wm = wave >> 1, wn = wave & 1;
    const int quad = lane >> 4, r16 = lane & 15;
    const int bx = blockIdx.x & 1, by = blockIdx.x >> 1;
    const int l4 = lane >> 2, lk = (lane & 3) * 8;

    f32x4 acc[4][4] = {};

    const __bf16* gA = A  + (size_t)(by * 128 + wave * 32 + l4) * K + lk;
    const __bf16* gB = Bw + (size_t)(bx * 128 + wave * 32 + l4) * K + lk;
    char* lA = (char*)As + wave * 2048;
    char* lB = (char*)Bs + wave * 2048;

    for (int k0 = 0; k0 < K; k0 += 32) {
        async_copy16(gA + k0,                  lA);
        async_copy16(gA + k0 + (size_t)16 * K, lA + 1024);
        async_copy16(gB + k0,                  lB);
        async_copy16(gB + k0 + (size_t)16 * K, lB + 1024);
        __syncthreads();

        bf16x8 af[4], bf[4];
#pragma unroll
        for (int t = 0; t < 4; ++t)
            af[t] = *(const bf16x8*)(As + (wm * 64 + t * 16 + r16) * 32 + quad * 8);
#pragma unroll
        for (int u = 0; u < 4; ++u)
            bf[u] = *(const bf16x8*)(Bs + (wn * 64 + u * 16 + r16) * 32 + quad * 8);
#pragma unroll
        for (int t = 0; t < 4; ++t)
#pragma unroll
            for (int u = 0; u < 4; ++u)
                acc[t][u] = __builtin_amdgcn_mfma_f32_16x16x32_bf16(af[t], bf[u], acc[t][u], 0, 0, 0);
        __syncthreads();
    }

    // C/D layout col=lane&15, row=(lane>>4)*4+reg [m89-verified]
#pragma unroll
    for (int t = 0; t < 4; ++t) {
#pragma unroll
        for (int u = 0; u < 4; ++u) {
            const int col = bx * 128 + wn * 64 + u * 16 + r16;
#pragma unroll
            for (int r = 0; r < 4; ++r) {
                const int row = by * 128 + wm * 64 + t * 16 + quad * 4 + r;
                Cout[(size_t)row * H_OUT + col] = (__bf16)acc[t][u][r];
            }
        }
    }

    if constexpr (STATS) {
        float* redS = (float*)As;          // [col(128)][slot(8)]
        float* redQ = ((float*)As) + 1024;
        const int slot = wm * 4 + quad;
#pragma unroll
        for (int u = 0; u < 4; ++u) {
            float s = 0.f, qq = 0.f;
#pragma unroll
            for (int t = 0; t < 4; ++t)
#pragma unroll
                for (int r = 0; r < 4; ++r) { float v = acc[t][u][r]; s += v; qq = fmaf(v, v, qq); }
            const int col = wn * 64 + u * 16 + r16;
            redS[col * 8 + slot] = s;
            redQ[col * 8 + slot] = qq;
        }
        __syncthreads();
        if (tid < 128) {
            float s = 0.f, qq = 0.f;
#pragma unroll
            for (int k = 0; k < 8; ++k) { s += redS[tid * 8 + k]; qq += redQ[tid * 8 + k]; }
            partS[(size_t)blockIdx.x * 128 + tid] = s;
            partQ[(size_t)blockIdx.x * 128 + tid] = qq;
        }
    }
}

// ---------------------------------------------------------------------------
// GEMM-A (K=128) + fused interpolation epilogue + BN-stats:
//   y1 = p1b @ wb1a^T + sum_k w_k * Z[idx_k]      (linearity of interp)
// Z rows are L2-resident (8.4 MB); gathers are 16-lane-contiguous 2B loads.
// grid = 512*2 = 1024 blocks of 256.  (idx/w come directly from knn_sweep.)
// ---------------------------------------------------------------------------
__global__ __launch_bounds__(256, 2) void gemm_a_int(
    const __bf16* __restrict__ A,  const __bf16* __restrict__ Bw,
    const __bf16* __restrict__ zb, const int4* __restrict__ gidx4,
    const float4* __restrict__ w4, __bf16* __restrict__ Cout,
    float* __restrict__ partS, float* __restrict__ partQ) {
    constexpr int K = C1;   // 128
    __shared__ __attribute__((aligned(16))) __bf16 As[128 * 32];
    __shared__ __attribute__((aligned(16))) __bf16 Bs[128 * 32];
    const int tid  = threadIdx.x;
    const int wave = tid >> 6, lane = tid & 63;
    const int wm = wave >> 1, wn = wave & 1;
    const int quad = lane >> 4, r16 = lane & 15;
    const int bx = blockIdx.x & 1, by = blockIdx.x >> 1;
    const int l4 = lane >> 2, lk = (lane & 3) * 8;

    f32x4 acc[4][4] = {};

    const __bf16* gA = A  + (size_t)(by * 128 + wave * 32 + l4) * K + lk;
    const __bf16* gB = Bw + (size_t)(bx * 128 + wave * 32 + l4) * K + lk;
    char* lA = (char*)As + wave * 2048;
    char* lB = (char*)Bs + wave * 2048;

    for (int k0 = 0; k0 < K; k0 += 32) {
        async_copy16(gA + k0,                  lA);
        async_copy16(gA + k0 + (size_t)16 * K, lA + 1024);
        async_copy16(gB + k0,                  lB);
        async_copy16(gB + k0 + (size_t)16 * K, lB + 1024);
        __syncthreads();

        bf16x8 af[4], bf[4];
#pragma unroll
        for (int t = 0; t < 4; ++t)
            af[t] = *(const bf16x8*)(As + (wm * 64 + t * 16 + r16) * 32 + quad * 8);
#pragma unroll
        for (int u = 0; u < 4; ++u)
            bf[u] = *(const bf16x8*)(Bs + (wn * 64 + u * 16 + r16) * 32 + quad * 8);
#pragma unroll
        for (int t = 0; t < 4; ++t)
#pragma unroll
            for (int u = 0; u < 4; ++u)
                acc[t][u] = __builtin_amdgcn_mfma_f32_16x16x32_bf16(af[t], bf[u], acc[t][u], 0, 0, 0);
        __syncthreads();
    }

    // stage per-row (idx0..2, w0..2) into As (4 KB of the free 8 KB)
    if (tid < 128) {
        const int q = by * 128 + tid;
        ((int4*)As)[tid * 2]       = gidx4[q];
        ((float4*)As)[tid * 2 + 1] = w4[q];
    }
    __syncthreads();

    // add interpolated Z rows into the accumulators
    const int bbase = (by >> 6) * M_PT;   // 64 row-blocks per batch
#pragma unroll
    for (int t = 0; t < 4; ++t) {
#pragma unroll
        for (int r = 0; r < 4; ++r) {
            const int rl = wm * 64 + t * 16 + quad * 4 + r;   // row-in-block
            const int4   ii = ((const int4*)As)[rl * 2];      // broadcast read
            const float4 ww = ((const float4*)As)[rl * 2 + 1];
            const __bf16* z0 = zb + (size_t)(bbase + ii.x) * H_OUT;
            const __bf16* z1 = zb + (size_t)(bbase + ii.y) * H_OUT;
            const __bf16* z2 = zb + (size_t)(bbase + ii.z) * H_OUT;
#pragma unroll
            for (int u = 0; u < 4; ++u) {
                const int col = bx * 128 + wn * 64 + u * 16 + r16;
                acc[t][u][r] += ww.x * (float)z0[col] + ww.y * (float)z1[col]
                              + ww.z * (float)z2[col];
            }
        }
    }

    // C store (bf16 y1)
#pragma unroll
    for (int t = 0; t < 4; ++t) {
#pragma unroll
        for (int u = 0; u < 4; ++u) {
            const int col = bx * 128 + wn * 64 + u * 16 + r16;
#pragma unroll
            for (int r = 0; r < 4; ++r) {
                const int row = by * 128 + wm * 64 + t * 16 + quad * 4 + r;
                Cout[(size_t)row * H_OUT + col] = (__bf16)acc[t][u][r];
            }
        }
    }

    __syncthreads();   // idx/w reads done before stats overwrite As
    float* redS = (float*)As;
    float* redQ = ((float*)As) + 1024;
    const int slot = wm * 4 + quad;
#pragma unroll
    for (int u = 0; u < 4; ++u) {
        float s = 0.f, qq = 0.f;
#pragma unroll
        for (int t = 0; t < 4; ++t)
#pragma unroll
            for (int r = 0; r < 4; ++r) { float v = acc[t][u][r]; s += v; qq = fmaf(v, v, qq); }
        const int col = wn * 64 + u * 16 + r16;
        redS[col * 8 + slot] = s;
        redQ[col * 8 + slot] = qq;
    }
    __syncthreads();
    if (tid < 128) {
        float s = 0.f, qq = 0.f;
#pragma unroll
        for (int k = 0; k < 8; ++k) { s += redS[tid * 8 + k]; qq += redQ[tid * 8 + k]; }
        partS[(size_t)blockIdx.x * 128 + tid] = s;
        partQ[(size_t)blockIdx.x * 128 + tid] = qq;
    }
}

// ---------------------------------------------------------------------------
// fold per-block partials -> per-channel scale/shift.  One block per channel.
// channel c lives in gemm-blocks bid = p*2 + (c>>7), entry (c&127); p<512.
// ---------------------------------------------------------------------------
__global__ __launch_bounds__(256) void bn_finalize(const float* __restrict__ pS,
                                                   const float* __restrict__ pQ,
                                                   const float* __restrict__ gamma,
                                                   const float* __restrict__ beta,
                                                   float* __restrict__ sc,
                                                   float* __restrict__ sh) {
    __shared__ float rs[256], rq[256];
    const int c = blockIdx.x;
    const int t = threadIdx.x;
    const int half = c >> 7, lo = c & 127;
    const size_t o1 = (size_t)(2 * t + half) * 128 + lo;
    const size_t o2 = (size_t)(2 * (t + 256) + half) * 128 + lo;
    rs[t] = pS[o1] + pS[o2];
    rq[t] = pQ[o1] + pQ[o2];
    __syncthreads();
    for (int k = 128; k > 0; k >>= 1) {
        if (t < k) { rs[t] += rs[t + k]; rq[t] += rq[t + k]; }
        __syncthreads();
    }
    if (t == 0) {
        const float inv = 1.f / (float)R_TOT;
        float mean = rs[0] * inv;
        float var  = rq[0] * inv - mean * mean;
        float a    = gamma[c] * rsqrtf(var + 1e-5f);
        sc[c] = a;
        sh[c] = beta[c] - mean * a;
    }
}

// ---------------------------------------------------------------------------
// apply BN+ReLU in place (bf16, layer-1 intermediate)
// ---------------------------------------------------------------------------
__global__ __launch_bounds__(256) void apply_bf16(__bf16* __restrict__ y,
                                                  const float* __restrict__ sc,
                                                  const float* __restrict__ sh) {
    __shared__ float scs[256], shs[256];
    scs[threadIdx.x] = sc[threadIdx.x];
    shs[threadIdx.x] = sh[threadIdx.x];
    __syncthreads();
    size_t i = ((size_t)blockIdx.x * 256 + threadIdx.x) * 8;
    int c0 = (int)(i & 255);
    bf16x8 v = *(const bf16x8*)(y + i);
#pragma unroll
    for (int e = 0; e < 8; ++e) {
        float f = fmaf((float)v[e], scs[c0 + e], shs[c0 + e]);
        v[e] = (__bf16)fmaxf(f, 0.f);
    }
    *(bf16x8*)(y + i) = v;
}

// ---------------------------------------------------------------------------
// apply BN+ReLU reading bf16 y2, writing fp32 output
// ---------------------------------------------------------------------------
__global__ __launch_bounds__(256) void apply_out(const __bf16* __restrict__ y,
                                                 const float* __restrict__ sc,
                                                 const float* __restrict__ sh,
                                                 float* __restrict__ out) {
    __shared__ float scs[256], shs[256];
    scs[threadIdx.x] = sc[threadIdx.x];
    shs[threadIdx.x] = sh[threadIdx.x];
    __syncthreads();
    size_t i = ((size_t)blockIdx.x * 256 + threadIdx.x) * 8;
    int c0 = (int)(i & 255);
    bf16x8 v = *(const bf16x8*)(y + i);
    f32x4 o0, o1;
#pragma unroll
    for (int e = 0; e < 4; ++e)
        o0[e] = fmaxf(fmaf((float)v[e], scs[c0 + e], shs[c0 + e]), 0.f);
#pragma unroll
    for (int e = 0; e < 4; ++e)
        o1[e] = fmaxf(fmaf((float)v[4 + e], scs[c0 + 4 + e], shs[c0 + 4 + e]), 0.f);
    *(f32x4*)(out + i)     = o0;
    *(f32x4*)(out + i + 4) = o1;
}

// ---------------------------------------------------------------------------
extern "C" void kernel_launch(void* const* d_in, const int* in_sizes, int n_in,
                              void* d_out, int out_size, void* d_ws, size_t ws_size,
                              hipStream_t stream) {
    const float* xyz1 = (const float*)d_in[0];
    const float* xyz2 = (const float*)d_in[1];
    const float* p1   = (const float*)d_in[2];
    const float* p2   = (const float*)d_in[3];
    const float* W1   = (const float*)d_in[4];
    // d_in[5] = b1  (cancels in batch-norm)
    const float* g1   = (const float*)d_in[6];
    const float* be1  = (const float*)d_in[7];
    const float* W2   = (const float*)d_in[8];
    // d_in[9] = b2  (cancels in batch-norm)
    const float* g2   = (const float*)d_in[10];
    const float* be2  = (const float*)d_in[11];
    float* out = (float*)d_out;

    // workspace layout (16B aligned), max ~76.9 MB:
    //   gidx4/spts/sidx/pcdf live in the y2b overlay region (all dead after
    //   gemm_a_int / knn_sweep, before gemm_bt<H_OUT> writes y2b)
    char* ws = (char*)d_ws;
    __bf16* y1b   = (__bf16*)(ws);                     // 33,554,432
    int4*   gidx4 = (int4*)  (ws + 33554432);          //  1,048,576
    float4* spts  = (float4*)(ws + 34603008);          //    262,144
    int*    sidx  = (int*)   (ws + 34865152);          //     65,536
    int*    pcdf  = (int*)   (ws + 34930688);          //      8,192
    __bf16* zb    = (__bf16*)(ws + 41943040);          //  8,388,608
    float4* w4    = (float4*)(ws + 50331648);          //  1,048,576
    __bf16* p2b   = (__bf16*)(ws + 51380224);          //  8,388,608
    __bf16* p1b   = (__bf16*)(ws + 59768832);          // 16,777,216
    __bf16* y2b   = (__bf16*)(ws + 33554432);          // 33,554,432 (overlay)
    __bf16* wb1a  = (__bf16*)(ws + 76546048);          //     65,536
    __bf16* wb1b  = (__bf16*)(ws + 76611584);          //    131,072
    __bf16* wb2   = (__bf16*)(ws + 76742656);          //    131,072
    float*  sc1   = (float*) (ws + 76873728);
    float*  sh1   = sc1 + 256;
    float*  sc2   = sc1 + 512;
    float*  sh2   = sc1 + 768;

    float* partS1 = (float*)d_out;            // d_out dead until apply_out
    float* partQ1 = partS1 + 131072;
    float* partS2 = partS1 + 262144;
    float* partQ2 = partS1 + 393216;

    convert_sort<<<712, 256, 0, stream>>>(xyz2, W1, W2, wb1a, wb1b, wb2,
                                          spts, sidx, pcdf);
    knn_sweep<<<2048, 256, 0, stream>>>(xyz1, spts, sidx, pcdf,
                                        p1, p2, p1b, p2b, w4, gidx4);

    gemm_bt<C2, false><<<256, 256, 0, stream>>>(p2b, wb1b, zb, nullptr, nullptr);
    gemm_a_int<<<1024, 256, 0, stream>>>(p1b, wb1a, zb, gidx4, w4, y1b,
                                         partS1, partQ1);
    bn_finalize<<<256, 256, 0, stream>>>(partS1, partQ1, g1, be1, sc1, sh1);
    apply_bf16<<<8192, 256, 0, stream>>>(y1b, sc1, sh1);

    gemm_bt<H_OUT, true><<<1024, 256, 0, stream>>>(y1b, wb2, y2b, partS2, partQ2);
    bn_finalize<<<256, 256, 0, stream>>>(partS2, partQ2, g2, be2, sc2, sh2);
    apply_out<<<8192, 256, 0, stream>>>(y2b, sc2, sh2, out);
}